// Round 1
// baseline (312.735 us; speedup 1.0000x reference)
//
#include <hip/hip_runtime.h>
#include <stdint.h>

#define BB 2
#define TT 2048
#define DD 2048
#define NHD 16
#define KVH 8
#define HD 128
#define JC 4096          // qkv gemm output cols: q 2048 | k 1024 | v 1024
#define WIN 1024
#define SCALE_Q 0.08838834764831845f  // 1/sqrt(128)

typedef __attribute__((ext_vector_type(8))) short bf16x8;
typedef __attribute__((ext_vector_type(8))) unsigned short us8;
typedef __attribute__((ext_vector_type(4))) unsigned short us4;
typedef __attribute__((ext_vector_type(4))) float f32x4;

#define GAS __attribute__((address_space(1)))
#define LAS __attribute__((address_space(3)))

__device__ __forceinline__ unsigned short f2bf(float f) {
  unsigned u = __float_as_uint(f);
  u += 0x7FFFu + ((u >> 16) & 1u);   // RNE
  return (unsigned short)(u >> 16);
}

__device__ __forceinline__ void gload16(const void* g, void* l) {
  __builtin_amdgcn_global_load_lds((const GAS unsigned int*)g, (LAS unsigned int*)l, 16, 0, 0);
}

// ---------------- elementwise fp32 -> bf16 ----------------
__global__ void __launch_bounds__(256) k_cvt(const float4* __restrict__ in,
                                             us4* __restrict__ out, int n4) {
  int i = blockIdx.x * 256 + threadIdx.x;
  if (i >= n4) return;
  float4 v = in[i];
  us4 o;
  o[0] = f2bf(v.x); o[1] = f2bf(v.y); o[2] = f2bf(v.z); o[3] = f2bf(v.w);
  out[i] = o;
}

// ---------------- batched transpose + convert ----------------
// in: batch z at in + (z/nbi)*b0s + (z%nbi)*b1s, R x C fp32 rows of stride ldin
// out: batch z at out + z*obs, C x R bf16 row-major
__global__ void __launch_bounds__(256) k_transpose_cvt(
    const float* __restrict__ in, unsigned short* __restrict__ out,
    int R, int C, int ldin, long b0s, int nbi, long b1s, long obs) {
  __shared__ float tile[32][33];
  int z = blockIdx.z;
  const float* ib = in + (long)(z / nbi) * b0s + (long)(z % nbi) * b1s;
  unsigned short* ob = out + (long)z * obs;
  int c0 = blockIdx.x * 32, r0 = blockIdx.y * 32;
  int tx = threadIdx.x, ty = threadIdx.y;
#pragma unroll
  for (int i = 0; i < 4; i++)
    tile[ty + i * 8][tx] = ib[(long)(r0 + ty + i * 8) * ldin + c0 + tx];
  __syncthreads();
#pragma unroll
  for (int i = 0; i < 4; i++)
    ob[(long)(c0 + ty + i * 8) * R + r0 + tx] = f2bf(tile[tx][ty + i * 8]);
}

// ---------------- bf16 GEMM: C[M,N] = A[M,K] * Bt[N,K]^T (m97 structure) ----------------
__global__ void __launch_bounds__(256, 2) k_gemm_bt(
    const unsigned short* __restrict__ A, const unsigned short* __restrict__ Bt,
    float* __restrict__ C, int M, int Nn, int Kd) {
  __shared__ short As[128 * 32];
  __shared__ short Bs[128 * 32];
  int tid = threadIdx.x;
  int lane = tid & 63, wid = tid >> 6;
  int wr = wid >> 1, wc = wid & 1;
  int m0 = blockIdx.x * 128, n0 = blockIdx.y * 128;
  f32x4 acc[4][4] = {};

  for (int ko = 0; ko < Kd; ko += 32) {
#pragma unroll
    for (int c = 0; c < 2; ++c) {
      int ch = wid * 2 + c;                 // chunk 0..7: rows [ch*16, ch*16+16)
      int row = ch * 16 + (lane >> 2);
      int col = (lane & 3) * 8;
      gload16(A + (long)(m0 + row) * Kd + ko + col, &As[ch * 512]);
      gload16(Bt + (long)(n0 + row) * Kd + ko + col, &Bs[ch * 512]);
    }
    __syncthreads();
    bf16x8 af[4], bf[4];
#pragma unroll
    for (int mi = 0; mi < 4; mi++)
      af[mi] = *(const bf16x8*)&As[(wr * 64 + mi * 16 + (lane & 15)) * 32 + (lane >> 4) * 8];
#pragma unroll
    for (int ni = 0; ni < 4; ni++)
      bf[ni] = *(const bf16x8*)&Bs[(wc * 64 + ni * 16 + (lane & 15)) * 32 + (lane >> 4) * 8];
#pragma unroll
    for (int mi = 0; mi < 4; mi++)
#pragma unroll
      for (int ni = 0; ni < 4; ni++)
        acc[mi][ni] = __builtin_amdgcn_mfma_f32_16x16x32_bf16(af[mi], bf[ni], acc[mi][ni], 0, 0, 0);
    __syncthreads();
  }
#pragma unroll
  for (int mi = 0; mi < 4; mi++)
#pragma unroll
    for (int ni = 0; ni < 4; ni++)
#pragma unroll
      for (int r = 0; r < 4; r++) {
        int row = m0 + wr * 64 + mi * 16 + (lane >> 4) * 4 + r;
        int col = n0 + wc * 64 + ni * 16 + (lane & 15);
        C[(long)row * Nn + col] = acc[mi][ni][r];
      }
}

// ---------------- RMSNorm + RoPE (+SCALE for q), fp32 -> bf16, head-major out ----------------
__global__ void __launch_bounds__(256) k_norm_rope(
    const float* __restrict__ qkv, const float* __restrict__ qns, const float* __restrict__ kns,
    unsigned short* __restrict__ qb, unsigned short* __restrict__ kb) {
  int wid = threadIdx.x >> 6, lane = threadIdx.x & 63;
  long r = (long)blockIdx.x * 4 + wid;          // over B*T*24 rows (16 q + 8 k heads)
  int b = (int)(r / (TT * 24));
  int rem = (int)(r % (TT * 24));
  int t = rem / 24, hd = rem % 24;
  const float* row = qkv + (long)(b * TT + t) * JC + (hd < 16 ? hd * HD : 2048 + (hd - 16) * HD);
  float f0 = row[lane], f1 = row[lane + 64];
  float ss = f0 * f0 + f1 * f1;
#pragma unroll
  for (int m = 1; m < 64; m <<= 1) ss += __shfl_xor(ss, m, 64);
  float rinv = rsqrtf(ss * (1.0f / 128.0f) + 1e-6f);
  const float* sc = (hd < 16) ? qns : kns;
  float y0 = f0 * rinv * (1.0f + sc[lane]);
  float y1 = f1 * rinv * (1.0f + sc[lane + 64]);
  // rope: pair index = lane, timescale = 10000^(lane/64)
  float ts = powf(10000.0f, (float)lane * (1.0f / 64.0f));
  float ang = (float)t / ts;
  float s, c;
  sincosf(ang, &s, &c);
  float o0 = y0 * c - y1 * s;
  float o1 = y1 * c + y0 * s;
  unsigned short* dst;
  if (hd < 16) {
    o0 *= SCALE_Q; o1 *= SCALE_Q;
    dst = qb + ((long)(b * NHD + hd) * TT + t) * HD;
  } else {
    dst = kb + ((long)(b * KVH + (hd - 16)) * TT + t) * HD;
  }
  dst[lane] = f2bf(o0);
  dst[lane + 64] = f2bf(o1);
}

// ---------------- flash attention: QBLK=64 (4 waves x 16 rows), KVBLK=32 ----------------
// qb: (B,N,T,H) bf16; kb: (B,KH,T,H) bf16; vbT: (B,KH,H,T) bf16; enc: (B,T,N,H) bf16
__global__ void __launch_bounds__(256, 2) k_attn(
    const unsigned short* __restrict__ qb, const unsigned short* __restrict__ kb,
    const unsigned short* __restrict__ vbT, unsigned short* __restrict__ enc) {
  __shared__ short Kl[32][136];    // padded: kills stride-256B bank conflicts
  __shared__ short Vt[128][40];    // [dim][s], padded
  __shared__ short Pl[4][16][40];  // per-wave P re-layout buffer
  int tid = threadIdx.x, lane = tid & 63, w = tid >> 6;
  int b = blockIdx.z, n = blockIdx.y, t0 = blockIdx.x * 64;
  int kh = n >> 1;  // G=2
  const unsigned short* qbase = qb + (long)(b * NHD + n) * TT * HD;
  const unsigned short* kbase = kb + (long)(b * KVH + kh) * TT * HD;
  const unsigned short* vbase = vbT + (long)(b * KVH + kh) * HD * TT;

  // Q fragments (A layout: row = lane&15, k = kk*32 + (lane>>4)*8 + j)
  int qrow = t0 + w * 16 + (lane & 15);
  bf16x8 aq[4];
#pragma unroll
  for (int kk = 0; kk < 4; kk++)
    aq[kk] = *(const bf16x8*)(qbase + (long)qrow * HD + kk * 32 + (lane >> 4) * 8);

  f32x4 acc[8] = {};
  float m[4], l[4];
#pragma unroll
  for (int r = 0; r < 4; r++) { m[r] = -3.0e38f; l[r] = 0.0f; }
  int trow_c = t0 + w * 16 + (lane >> 4) * 4;  // C-layout row base (+reg)
  int s_begin = (t0 >= WIN) ? (t0 - WIN) : 0;

  for (int s0 = s_begin; s0 < t0 + 64; s0 += 32) {
    {  // stage K tile [32][128] (linear, padded rows) and V tile [128][32]
      int row = tid >> 3, col0 = (tid & 7) * 16;
      const unsigned short* g = kbase + (long)(s0 + row) * HD + col0;
      *(us8*)&Kl[row][col0] = *(const us8*)g;
      *(us8*)&Kl[row][col0 + 8] = *(const us8*)(g + 8);
      int dim = tid >> 1, sc0 = (tid & 1) * 16;
      const unsigned short* gv = vbase + (long)dim * TT + s0 + sc0;
      *(us8*)&Vt[dim][sc0] = *(const us8*)gv;
      *(us8*)&Vt[dim][sc0 + 8] = *(const us8*)(gv + 8);
    }
    __syncthreads();

    // S = Q K^T (two 16-key blocks)
    f32x4 sacc[2] = {};
#pragma unroll
    for (int kblk = 0; kblk < 2; kblk++)
#pragma unroll
      for (int kk = 0; kk < 4; kk++) {
        bf16x8 bk = *(const bf16x8*)&Kl[kblk * 16 + (lane & 15)][kk * 32 + (lane >> 4) * 8];
        sacc[kblk] = __builtin_amdgcn_mfma_f32_16x16x32_bf16(aq[kk], bk, sacc[kblk], 0, 0, 0);
      }

    // soft-cap + mask + online softmax (C layout: col=lane&15, row=(lane>>4)*4+reg)
    float p[2][4], vmax[4];
#pragma unroll
    for (int r = 0; r < 4; r++) vmax[r] = -3.0e38f;
    int scol = s0 + (lane & 15);
#pragma unroll
    for (int kblk = 0; kblk < 2; kblk++) {
      int s_idx = scol + kblk * 16;
#pragma unroll
      for (int r = 0; r < 4; r++) {
        float x = sacc[kblk][r];
        float a = x * 0.02f;
        float e = __expf(-2.0f * fabsf(a));
        float th = (1.0f - e) * __builtin_amdgcn_rcpf(1.0f + e);
        th = copysignf(th, a) * 50.0f;
        int trow = trow_c + r;
        bool valid = (s_idx <= trow) && (s_idx > trow - WIN);
        p[kblk][r] = valid ? th : -3.0e38f;
        vmax[r] = fmaxf(vmax[r], p[kblk][r]);
      }
    }
#pragma unroll
    for (int r = 0; r < 4; r++) {
#pragma unroll
      for (int msk = 8; msk >= 1; msk >>= 1)
        vmax[r] = fmaxf(vmax[r], __shfl_xor(vmax[r], msk, 64));
      float mn = fmaxf(m[r], vmax[r]);
      float scale = __expf(m[r] - mn);   // both -3e38 -> exp(0)=1; -3e38->finite -> 0
      m[r] = mn;
      l[r] *= scale;
#pragma unroll
      for (int cb = 0; cb < 8; cb++) acc[cb][r] *= scale;
      float ps = 0.0f;
#pragma unroll
      for (int kblk = 0; kblk < 2; kblk++) {
        float pv = (p[kblk][r] > -1.0e37f) ? __expf(p[kblk][r] - mn) : 0.0f;
        p[kblk][r] = pv;
        ps += pv;
      }
#pragma unroll
      for (int msk = 8; msk >= 1; msk >>= 1) ps += __shfl_xor(ps, msk, 64);
      l[r] += ps;
    }

    // P -> per-wave LDS (C layout in, A layout out)
#pragma unroll
    for (int kblk = 0; kblk < 2; kblk++)
#pragma unroll
      for (int r = 0; r < 4; r++)
        Pl[w][(lane >> 4) * 4 + r][kblk * 16 + (lane & 15)] = (short)f2bf(p[kblk][r]);

    bf16x8 ap = *(const bf16x8*)&Pl[w][lane & 15][(lane >> 4) * 8];
#pragma unroll
    for (int cb = 0; cb < 8; cb++) {
      bf16x8 bv = *(const bf16x8*)&Vt[cb * 16 + (lane & 15)][(lane >> 4) * 8];
      acc[cb] = __builtin_amdgcn_mfma_f32_16x16x32_bf16(ap, bv, acc[cb], 0, 0, 0);
    }
    __syncthreads();
  }

  // epilogue: enc[b,t,n,h] bf16
#pragma unroll
  for (int r = 0; r < 4; r++) {
    float inv = __builtin_amdgcn_rcpf(l[r]);
    int trow = trow_c + r;
    unsigned short* dst = enc + ((long)(b * TT + trow) * NHD + n) * HD;
#pragma unroll
    for (int cb = 0; cb < 8; cb++)
      dst[cb * 16 + (lane & 15)] = f2bf(acc[cb][r] * inv);
  }
}

extern "C" void kernel_launch(void* const* d_in, const int* in_sizes, int n_in,
                              void* d_out, int out_size, void* d_ws, size_t ws_size,
                              hipStream_t stream) {
  const float* x    = (const float*)d_in[0];
  const float* q_w  = (const float*)d_in[1];
  const float* kv_w = (const float*)d_in[2];
  const float* o_w  = (const float*)d_in[3];
  const float* qns  = (const float*)d_in[4];
  const float* kns  = (const float*)d_in[5];
  // d_in[6] segment_pos (arange), d_in[7] attn_mask (tril) -- realized analytically

  if (ws_size < (104ull << 20)) return;  // need 104 MB scratch
  char* ws = (char*)d_ws;
  float*          qkv  = (float*)(ws + 0);                      // 64 MB (dead after norm/vT)
  unsigned short* enc  = (unsigned short*)(ws + 0);             // alias over dead qkv
  unsigned short* x_bf = (unsigned short*)(ws + (64ll << 20));  // 16 MB (dead after gemm1)
  unsigned short* qb   = (unsigned short*)(ws + (64ll << 20));  // alias over dead x_bf
  unsigned short* Wt   = (unsigned short*)(ws + (80ll << 20));  // 16 MB (dead after gemm1)
  unsigned short* kb   = (unsigned short*)(ws + (80ll << 20));  // alias over dead Wt
  unsigned short* vbT  = (unsigned short*)(ws + (88ll << 20));  // alias over dead Wt
  unsigned short* Wt_o = (unsigned short*)(ws + (96ll << 20));  // 8 MB, persists

  dim3 tb(32, 8, 1);
  // x -> bf16
  k_cvt<<<8192, 256, 0, stream>>>((const float4*)x, (us4*)x_bf, 2097152);
  // weights -> B^T bf16 layouts
  k_transpose_cvt<<<dim3(4, 64, 16), tb, 0, stream>>>(q_w, Wt, 2048, 128, 128,
                                                      0, 16, (long)2048 * 128, (long)128 * 2048);
  k_transpose_cvt<<<dim3(4, 64, 8), tb, 0, stream>>>(kv_w, Wt + (long)2048 * 2048, 2048, 128, 128,
                                                     0, 8, (long)2048 * 128, (long)128 * 2048);
  k_transpose_cvt<<<dim3(4, 64, 8), tb, 0, stream>>>(kv_w + (long)8 * 2048 * 128, Wt + (long)3072 * 2048,
                                                     2048, 128, 128, 0, 8, (long)2048 * 128, (long)128 * 2048);
  k_transpose_cvt<<<dim3(64, 64, 1), tb, 0, stream>>>(o_w, Wt_o, 2048, 2048, 2048, 0, 1, 0, 0);
  // qkv = x @ W  (fp32 out)
  k_gemm_bt<<<dim3(32, 32), 256, 0, stream>>>(x_bf, Wt, qkv, 4096, 4096, 2048);
  // v -> (B,KH,H,T) bf16
  k_transpose_cvt<<<dim3(4, 64, 16), tb, 0, stream>>>(qkv + 3072, vbT, 2048, 128, 4096,
                                                      (long)2048 * 4096, 8, 128, (long)128 * 2048);
  // rmsnorm + rope -> qb, kb
  k_norm_rope<<<24576, 256, 0, stream>>>(qkv, qns, kns, qb, kb);
  // attention -> enc (bf16)
  k_attn<<<dim3(32, 16, 2), 256, 0, stream>>>(qb, kb, vbT, enc);
  // out = enc @ o_w  (fp32 straight to d_out)
  k_gemm_bt<<<dim3(32, 16), 256, 0, stream>>>(enc, Wt_o, (float*)d_out, 4096, 2048, 2048);
}

// Round 2
// 243.432 us; speedup vs baseline: 1.2847x; 1.2847x over previous
//
#include <hip/hip_runtime.h>
#include <stdint.h>

#define BB 2
#define TT 2048
#define DD 2048
#define NHD 16
#define KVH 8
#define HD 128
#define JC 4096          // qkv gemm output cols: q 2048 | k 1024 | v 1024
#define WIN 1024
#define SCALE_Q 0.08838834764831845f  // 1/sqrt(128)

typedef __attribute__((ext_vector_type(8))) short bf16x8;
typedef __attribute__((ext_vector_type(8))) unsigned short us8;
typedef __attribute__((ext_vector_type(4))) unsigned short us4;
typedef __attribute__((ext_vector_type(4))) float f32x4;
typedef __attribute__((ext_vector_type(16))) float f32x16;
typedef __attribute__((ext_vector_type(4))) unsigned int u32x4;

#define GAS __attribute__((address_space(1)))
#define LAS __attribute__((address_space(3)))

__device__ __forceinline__ unsigned short f2bf(float f) {
  unsigned u = __float_as_uint(f);
  u += 0x7FFFu + ((u >> 16) & 1u);   // RNE
  return (unsigned short)(u >> 16);
}

__device__ __forceinline__ void gload16(const void* g, void* l) {
  __builtin_amdgcn_global_load_lds((const GAS unsigned int*)g, (LAS unsigned int*)l, 16, 0, 0);
}

// ---------------- elementwise fp32 -> bf16 ----------------
__global__ void __launch_bounds__(256) k_cvt(const float4* __restrict__ in,
                                             us4* __restrict__ out, int n4) {
  int i = blockIdx.x * 256 + threadIdx.x;
  if (i >= n4) return;
  float4 v = in[i];
  us4 o;
  o[0] = f2bf(v.x); o[1] = f2bf(v.y); o[2] = f2bf(v.z); o[3] = f2bf(v.w);
  out[i] = o;
}

// ---------------- batched transpose + convert ----------------
__global__ void __launch_bounds__(256) k_transpose_cvt(
    const float* __restrict__ in, unsigned short* __restrict__ out,
    int R, int C, int ldin, long b0s, int nbi, long b1s, long obs) {
  __shared__ float tile[32][33];
  int z = blockIdx.z;
  const float* ib = in + (long)(z / nbi) * b0s + (long)(z % nbi) * b1s;
  unsigned short* ob = out + (long)z * obs;
  int c0 = blockIdx.x * 32, r0 = blockIdx.y * 32;
  int tx = threadIdx.x, ty = threadIdx.y;
#pragma unroll
  for (int i = 0; i < 4; i++)
    tile[ty + i * 8][tx] = ib[(long)(r0 + ty + i * 8) * ldin + c0 + tx];
  __syncthreads();
#pragma unroll
  for (int i = 0; i < 4; i++)
    ob[(long)(c0 + ty + i * 8) * R + r0 + tx] = f2bf(tile[tx][ty + i * 8]);
}

// ---------------- bf16 GEMM: C[M,N] = A[M,K] * Bt[N,K]^T (m97 structure) ----------------
__global__ void __launch_bounds__(256, 2) k_gemm_bt(
    const unsigned short* __restrict__ A, const unsigned short* __restrict__ Bt,
    float* __restrict__ C, int M, int Nn, int Kd) {
  __shared__ short As[128 * 32];
  __shared__ short Bs[128 * 32];
  int tid = threadIdx.x;
  int lane = tid & 63, wid = tid >> 6;
  int wr = wid >> 1, wc = wid & 1;
  int m0 = blockIdx.x * 128, n0 = blockIdx.y * 128;
  f32x4 acc[4][4] = {};

  for (int ko = 0; ko < Kd; ko += 32) {
#pragma unroll
    for (int c = 0; c < 2; ++c) {
      int ch = wid * 2 + c;
      int row = ch * 16 + (lane >> 2);
      int col = (lane & 3) * 8;
      gload16(A + (long)(m0 + row) * Kd + ko + col, &As[ch * 512]);
      gload16(Bt + (long)(n0 + row) * Kd + ko + col, &Bs[ch * 512]);
    }
    __syncthreads();
    bf16x8 af[4], bf[4];
#pragma unroll
    for (int mi = 0; mi < 4; mi++)
      af[mi] = *(const bf16x8*)&As[(wr * 64 + mi * 16 + (lane & 15)) * 32 + (lane >> 4) * 8];
#pragma unroll
    for (int ni = 0; ni < 4; ni++)
      bf[ni] = *(const bf16x8*)&Bs[(wc * 64 + ni * 16 + (lane & 15)) * 32 + (lane >> 4) * 8];
#pragma unroll
    for (int mi = 0; mi < 4; mi++)
#pragma unroll
      for (int ni = 0; ni < 4; ni++)
        acc[mi][ni] = __builtin_amdgcn_mfma_f32_16x16x32_bf16(af[mi], bf[ni], acc[mi][ni], 0, 0, 0);
    __syncthreads();
  }
#pragma unroll
  for (int mi = 0; mi < 4; mi++)
#pragma unroll
    for (int ni = 0; ni < 4; ni++)
#pragma unroll
      for (int r = 0; r < 4; r++) {
        int row = m0 + wr * 64 + mi * 16 + (lane >> 4) * 4 + r;
        int col = n0 + wc * 64 + ni * 16 + (lane & 15);
        C[(long)row * Nn + col] = acc[mi][ni][r];
      }
}

// ---------------- RMSNorm + RoPE (+SCALE for q), fp32 -> bf16, head-major out ----------------
__global__ void __launch_bounds__(256) k_norm_rope(
    const float* __restrict__ qkv, const float* __restrict__ qns, const float* __restrict__ kns,
    unsigned short* __restrict__ qb, unsigned short* __restrict__ kb) {
  int wid = threadIdx.x >> 6, lane = threadIdx.x & 63;
  long r = (long)blockIdx.x * 4 + wid;
  int b = (int)(r / (TT * 24));
  int rem = (int)(r % (TT * 24));
  int t = rem / 24, hd = rem % 24;
  const float* row = qkv + (long)(b * TT + t) * JC + (hd < 16 ? hd * HD : 2048 + (hd - 16) * HD);
  float f0 = row[lane], f1 = row[lane + 64];
  float ss = f0 * f0 + f1 * f1;
#pragma unroll
  for (int m = 1; m < 64; m <<= 1) ss += __shfl_xor(ss, m, 64);
  float rinv = rsqrtf(ss * (1.0f / 128.0f) + 1e-6f);
  const float* sc = (hd < 16) ? qns : kns;
  float y0 = f0 * rinv * (1.0f + sc[lane]);
  float y1 = f1 * rinv * (1.0f + sc[lane + 64]);
  // timescale = 10000^(lane/64) = exp2(lane * log2(10000)/64)
  float ts = exp2f((float)lane * (13.287712379549449f / 64.0f));
  float ang = (float)t / ts;
  float s, c;
  sincosf(ang, &s, &c);
  float o0 = y0 * c - y1 * s;
  float o1 = y1 * c + y0 * s;
  unsigned short* dst;
  if (hd < 16) {
    o0 *= SCALE_Q; o1 *= SCALE_Q;
    dst = qb + ((long)(b * NHD + hd) * TT + t) * HD;
  } else {
    dst = kb + ((long)(b * KVH + (hd - 16)) * TT + t) * HD;
  }
  dst[lane] = f2bf(o0);
  dst[lane + 64] = f2bf(o1);
}

// ---------------- softcap -> p = exp(50*tanh(x/50) - 50) (fixed-max softmax) ----------------
// p = exp2(-144.2695 * u), u = (x>0 ? e : 1) * rcp(1+e), e = exp2(-0.0577078*|x|)
template <bool FULL>
__device__ __forceinline__ void softcap16(const f32x16& s16, float* pr, float& lsum,
                                          int s_base, int tq, int g) {
#pragma unroll
  for (int r = 0; r < 16; r++) {
    float x = s16[r];
    float e = __builtin_amdgcn_exp2f(-0.05770780163555853f * fabsf(x));
    float u = (x > 0.0f ? e : 1.0f) * __builtin_amdgcn_rcpf(1.0f + e);
    float p = __builtin_amdgcn_exp2f(-144.26950408889634f * u);
    if (!FULL) {
      int s = s_base + (r & 3) + 8 * (r >> 2) + 4 * g;
      bool valid = (s <= tq) && (s > tq - WIN);
      p = valid ? p : 0.0f;
    }
    lsum += p;
    pr[r] = p;
  }
}

// half-swap: returns (a',b') with a' = [a.lo | b.lo], b' = [a.hi | b.hi] across lane 32 boundary
__device__ __forceinline__ void hswap(unsigned& a, unsigned& b, int g) {
  unsigned ax = (unsigned)__shfl_xor((int)a, 32, 64);
  unsigned bx = (unsigned)__shfl_xor((int)b, 32, 64);
  unsigned r0 = g ? bx : a;
  unsigned r1 = g ? b : ax;
  a = r0; b = r1;
}

// ---------------- flash attention v2: QBLK=128 (4 waves x 32 rows), KVBLK=64, 32x32 MFMA ----
// Swapped QK^T (S^T = K*Q^T -> col=q lane-local softmax), fixed-max=50, in-register P^T.
// qb: (B,N,T,H) bf16; kb: (B,KH,T,H) bf16; vbT: (B,KH,H,T) bf16; enc: (B,T,N,H) bf16
__global__ void __launch_bounds__(256, 2) k_attn(
    const unsigned short* __restrict__ qb, const unsigned short* __restrict__ kb,
    const unsigned short* __restrict__ vbT, unsigned short* __restrict__ enc) {
  __shared__ short Kl[2][64][128];   // [buf][s][d], XOR-swizzled 16B chunks: c ^= (s&7)
  __shared__ short Vt[2][128][64];   // [buf][h][s], XOR-swizzled 16B chunks: c ^= (h&7)
  int tid = threadIdx.x, lane = tid & 63, w = tid >> 6;
  int g = lane >> 5, l31 = lane & 31;
  int id = blockIdx.x;
  int b = id >> 8;
  int rem = id & 255;
  int n = rem >> 4;
  int traw = rem & 15;
  int tile = b ? ((traw + 8) & 15) : traw;  // pair small+large work per CU slot
  int t0 = tile * 128;
  int kh = n >> 1;
  const unsigned short* qbase = qb + ((long)(b * NHD + n) * TT + t0 + w * 32) * HD;
  const unsigned short* kbase = kb + (long)(b * KVH + kh) * TT * HD;
  const unsigned short* vbase = vbT + (long)(b * KVH + kh) * HD * TT;

  // Q B-frags in registers: col=q=l31, k = kb8*16 + g*8 + j
  bf16x8 bq[8];
  {
    const unsigned short* qp = qbase + (long)l31 * HD + g * 8;
#pragma unroll
    for (int kb8 = 0; kb8 < 8; kb8++)
      bq[kb8] = *(const bf16x8*)(qp + kb8 * 16);
  }

  f32x16 acc[4] = {};   // enc^T: [ht] rows h=ht*32+(reg pattern), col q=l31
  float lsum = 0.0f;
  int t0w = t0 + w * 32;
  int tq = t0w + l31;
  int s_begin = (t0 >= WIN) ? t0 - WIN : 0;
  int s_end = t0 + 128;

  auto STAGE = [&](int buf, int s0) {
#pragma unroll
    for (int i = 0; i < 4; i++) {   // K: wave stages rows [w*16, w*16+16)
      int row = w * 16 + i * 4 + (lane >> 4);
      int c16 = (lane & 15) ^ (row & 7);
      gload16(kbase + (long)(s0 + row) * HD + c16 * 8, &Kl[buf][w * 16 + i * 4][0]);
    }
#pragma unroll
    for (int i = 0; i < 4; i++) {   // V: wave stages rows [w*32, w*32+32)
      int row = w * 32 + i * 8 + (lane >> 3);
      int c16 = (lane & 7) ^ (row & 7);
      gload16(vbase + (long)row * TT + s0 + c16 * 8, &Vt[buf][w * 32 + i * 8][0]);
    }
  };

  STAGE(0, s_begin);
  __syncthreads();
  int cur = 0;
  for (int s0 = s_begin; s0 < s_end; s0 += 64) {
    if (s0 + 64 < s_end) STAGE(cur ^ 1, s0 + 64);
    bool live = (s0 <= t0w + 31) && (s0 + 63 >= t0w - (WIN - 1));
    if (live) {
      // S^T = K * Q^T : 2 s-blocks x 8 k-slices
      f32x16 sc2[2] = {};
#pragma unroll
      for (int sb = 0; sb < 2; sb++) {
        int srow = sb * 32 + l31;
#pragma unroll
        for (int kb8 = 0; kb8 < 8; kb8++) {
          bf16x8 ak = *(const bf16x8*)&Kl[cur][srow][8 * ((2 * kb8 + g) ^ (srow & 7))];
          sc2[sb] = __builtin_amdgcn_mfma_f32_32x32x16_bf16(ak, bq[kb8], sc2[sb], 0, 0, 0);
        }
      }
      bool full = (s0 + 63 <= t0w) && (s0 >= t0w + 31 - (WIN - 1));
      unsigned pw[4][4];  // [ks][word] P^T B-frags
#pragma unroll
      for (int sb = 0; sb < 2; sb++) {
        float pr[16];
        if (full) softcap16<true>(sc2[sb], pr, lsum, 0, tq, g);
        else      softcap16<false>(sc2[sb], pr, lsum, s0 + sb * 32, tq, g);
        unsigned X[4], Y[4];
#pragma unroll
        for (int m = 0; m < 4; m++) {
          asm("v_cvt_pk_bf16_f32 %0, %1, %2" : "=v"(X[m]) : "v"(pr[4 * m]), "v"(pr[4 * m + 1]));
          asm("v_cvt_pk_bf16_f32 %0, %1, %2" : "=v"(Y[m]) : "v"(pr[4 * m + 2]), "v"(pr[4 * m + 3]));
        }
#pragma unroll
        for (int kl = 0; kl < 2; kl++) {
          hswap(X[2 * kl], X[2 * kl + 1], g);
          hswap(Y[2 * kl], Y[2 * kl + 1], g);
          pw[sb * 2 + kl][0] = X[2 * kl];
          pw[sb * 2 + kl][1] = Y[2 * kl];
          pw[sb * 2 + kl][2] = X[2 * kl + 1];
          pw[sb * 2 + kl][3] = Y[2 * kl + 1];
        }
      }
      // enc^T += V^T * P^T
#pragma unroll
      for (int ks = 0; ks < 4; ks++) {
        u32x4 t4 = {pw[ks][0], pw[ks][1], pw[ks][2], pw[ks][3]};
        bf16x8 pb = __builtin_bit_cast(bf16x8, t4);
#pragma unroll
        for (int ht = 0; ht < 4; ht++) {
          int hrow = ht * 32 + l31;
          bf16x8 av = *(const bf16x8*)&Vt[cur][hrow][8 * ((2 * ks + g) ^ (hrow & 7))];
          acc[ht] = __builtin_amdgcn_mfma_f32_32x32x16_bf16(av, pb, acc[ht], 0, 0, 0);
        }
      }
    }
    __syncthreads();
    cur ^= 1;
  }

  // epilogue: lane holds col q = tq; rows h = ht*32 + 8*r4 + 4g + e
  lsum += __shfl_xor(lsum, 32, 64);
  float inv = __builtin_amdgcn_rcpf(lsum);
  unsigned short* dst = enc + ((long)(b * TT + tq) * NHD + n) * HD;
#pragma unroll
  for (int ht = 0; ht < 4; ht++)
#pragma unroll
    for (int r4 = 0; r4 < 4; r4++) {
      us4 o;
#pragma unroll
      for (int e = 0; e < 4; e++) o[e] = f2bf(acc[ht][r4 * 4 + e] * inv);
      *(us4*)(dst + ht * 32 + 8 * r4 + 4 * g) = o;
    }
}

extern "C" void kernel_launch(void* const* d_in, const int* in_sizes, int n_in,
                              void* d_out, int out_size, void* d_ws, size_t ws_size,
                              hipStream_t stream) {
  const float* x    = (const float*)d_in[0];
  const float* q_w  = (const float*)d_in[1];
  const float* kv_w = (const float*)d_in[2];
  const float* o_w  = (const float*)d_in[3];
  const float* qns  = (const float*)d_in[4];
  const float* kns  = (const float*)d_in[5];

  if (ws_size < (104ull << 20)) return;
  char* ws = (char*)d_ws;
  float*          qkv  = (float*)(ws + 0);                      // 64 MB (dead after norm/vT)
  unsigned short* enc  = (unsigned short*)(ws + 0);             // alias over dead qkv
  unsigned short* x_bf = (unsigned short*)(ws + (64ll << 20));  // 16 MB (dead after gemm1)
  unsigned short* qb   = (unsigned short*)(ws + (64ll << 20));  // alias over dead x_bf
  unsigned short* Wt   = (unsigned short*)(ws + (80ll << 20));  // 16 MB (dead after gemm1)
  unsigned short* kb   = (unsigned short*)(ws + (80ll << 20));  // alias over dead Wt
  unsigned short* vbT  = (unsigned short*)(ws + (88ll << 20));  // alias over dead Wt
  unsigned short* Wt_o = (unsigned short*)(ws + (96ll << 20));  // 8 MB, persists

  dim3 tb(32, 8, 1);
  k_cvt<<<8192, 256, 0, stream>>>((const float4*)x, (us4*)x_bf, 2097152);
  k_transpose_cvt<<<dim3(4, 64, 16), tb, 0, stream>>>(q_w, Wt, 2048, 128, 128,
                                                      0, 16, (long)2048 * 128, (long)128 * 2048);
  k_transpose_cvt<<<dim3(4, 64, 8), tb, 0, stream>>>(kv_w, Wt + (long)2048 * 2048, 2048, 128, 128,
                                                     0, 8, (long)2048 * 128, (long)128 * 2048);
  k_transpose_cvt<<<dim3(4, 64, 8), tb, 0, stream>>>(kv_w + (long)8 * 2048 * 128, Wt + (long)3072 * 2048,
                                                     2048, 128, 128, 0, 8, (long)2048 * 128, (long)128 * 2048);
  k_transpose_cvt<<<dim3(64, 64, 1), tb, 0, stream>>>(o_w, Wt_o, 2048, 2048, 2048, 0, 1, 0, 0);
  k_gemm_bt<<<dim3(32, 32), 256, 0, stream>>>(x_bf, Wt, qkv, 4096, 4096, 2048);
  k_transpose_cvt<<<dim3(4, 64, 16), tb, 0, stream>>>(qkv + 3072, vbT, 2048, 128, 4096,
                                                      (long)2048 * 4096, 8, 128, (long)128 * 2048);
  k_norm_rope<<<24576, 256, 0, stream>>>(qkv, qns, kns, qb, kb);
  k_attn<<<512, 256, 0, stream>>>(qb, kb, vbT, enc);
  k_gemm_bt<<<dim3(32, 16), 256, 0, stream>>>(enc, Wt_o, (float*)d_out, 4096, 2048, 2048);
}

// Round 3
// 239.775 us; speedup vs baseline: 1.3043x; 1.0153x over previous
//
#include <hip/hip_runtime.h>
#include <stdint.h>

#define BB 2
#define TT 2048
#define DD 2048
#define NHD 16
#define KVH 8
#define HD 128
#define JC 4096          // qkv gemm output cols: q 2048 | k 1024 | v 1024
#define WIN 1024
#define SCALE_Q 0.08838834764831845f  // 1/sqrt(128)

typedef __attribute__((ext_vector_type(8))) short bf16x8;
typedef __attribute__((ext_vector_type(8))) unsigned short us8;
typedef __attribute__((ext_vector_type(4))) unsigned short us4;
typedef __attribute__((ext_vector_type(4))) float f32x4;
typedef __attribute__((ext_vector_type(16))) float f32x16;
typedef __attribute__((ext_vector_type(4))) unsigned int u32x4;

#define GAS __attribute__((address_space(1)))
#define LAS __attribute__((address_space(3)))

__device__ __forceinline__ unsigned short f2bf(float f) {
  unsigned u = __float_as_uint(f);
  u += 0x7FFFu + ((u >> 16) & 1u);   // RNE
  return (unsigned short)(u >> 16);
}

__device__ __forceinline__ void gload16(const void* g, void* l) {
  __builtin_amdgcn_global_load_lds((const GAS unsigned int*)g, (LAS unsigned int*)l, 16, 0, 0);
}

// ---------------- elementwise fp32 -> bf16 ----------------
__global__ void __launch_bounds__(256) k_cvt(const float4* __restrict__ in,
                                             us4* __restrict__ out, int n4) {
  int i = blockIdx.x * 256 + threadIdx.x;
  if (i >= n4) return;
  float4 v = in[i];
  us4 o;
  o[0] = f2bf(v.x); o[1] = f2bf(v.y); o[2] = f2bf(v.z); o[3] = f2bf(v.w);
  out[i] = o;
}

// ---------------- batched transpose + convert ----------------
__global__ void __launch_bounds__(256) k_transpose_cvt(
    const float* __restrict__ in, unsigned short* __restrict__ out,
    int R, int C, int ldin, long b0s, int nbi, long b1s, long obs) {
  __shared__ float tile[32][33];
  int z = blockIdx.z;
  const float* ib = in + (long)(z / nbi) * b0s + (long)(z % nbi) * b1s;
  unsigned short* ob = out + (long)z * obs;
  int c0 = blockIdx.x * 32, r0 = blockIdx.y * 32;
  int tx = threadIdx.x, ty = threadIdx.y;
#pragma unroll
  for (int i = 0; i < 4; i++)
    tile[ty + i * 8][tx] = ib[(long)(r0 + ty + i * 8) * ldin + c0 + tx];
  __syncthreads();
#pragma unroll
  for (int i = 0; i < 4; i++)
    ob[(long)(c0 + ty + i * 8) * R + r0 + tx] = f2bf(tile[tx][ty + i * 8]);
}

// ---------------- bf16 GEMM v2: phase-interleaved counted-vmcnt pipeline ----------------
// C[M,N] = A[M,K] * Bt[N,K]^T.  BM=256, BN=128, BK=64. 512 thr = 8 waves (4M x 2N),
// per-wave 64x64. 3 LDS buffers (144 KB), prefetch distance 2 tiles: stage t+2 while
// computing t -> staged buffer is never concurrently read; vmcnt(6) once per K-tile
// (= exactly the 6 in-flight loads of t+2) guarantees t+1 landed. Never drains in loop.
// LDS chunks XOR-swizzled (chunk ^= row&7) via pre-swizzled global source (rule #21).
__global__ void __launch_bounds__(512, 2) k_gemm8(
    const unsigned short* __restrict__ A, const unsigned short* __restrict__ Bt,
    float* __restrict__ C, int M, int Nn, int Kd, int nby) {
  __shared__ short lds[3][384 * 64];   // per buf: A [256 rows][64] @0, B [128 rows][64] @256*64
  int tid = threadIdx.x, lane = tid & 63, w = tid >> 6;
  int wm = w >> 1, wn = w & 1;
  int id = blockIdx.x;
  int cpx = gridDim.x >> 3;            // nwg % 8 == 0 for both call sites
  id = (id & 7) * cpx + (id >> 3);     // XCD-aware swizzle
  int m0 = (id / nby) * 256, n0 = (id % nby) * 128;
  const int NT = Kd >> 6;

  // stage loads j0..j1 of tile with k-origin ko into buffer sb
  auto STG = [&](int sb, int ko, int j0, int j1) {
#pragma unroll
    for (int j = j0; j <= j1; ++j) {
      int cdata = (lane & 7) ^ (lane >> 3);          // inverse-swizzled source chunk
      if (j < 4) {
        int rbase = j * 64 + w * 8;
        int row = rbase + (lane >> 3);
        gload16(A + (long)(m0 + row) * Kd + ko + cdata * 8, &lds[sb][rbase * 64]);
      } else {
        int rbase = (j - 4) * 64 + w * 8;
        int row = rbase + (lane >> 3);
        gload16(Bt + (long)(n0 + row) * Kd + ko + cdata * 8, &lds[sb][(256 + rbase) * 64]);
      }
    }
  };

  f32x4 acc[4][4] = {};
  // prologue: stage tiles 0 and 1, wait for tile 0 (6 of 12 loads in flight after)
  STG(0, 0, 0, 5);
  STG(1, 64, 0, 5);
  asm volatile("s_waitcnt vmcnt(6)" ::: "memory");
  __builtin_amdgcn_s_barrier();

  int buf = 0, sbuf = 2;
  for (int t = 0; t < NT; ++t) {
    bool st = (t + 2) < NT;
#pragma unroll
    for (int q = 0; q < 2; ++q) {
      // ds-load quadrant frags (swizzled read)
      bf16x8 af[2][2], bfr[4][2];
#pragma unroll
      for (int mi2 = 0; mi2 < 2; mi2++)
#pragma unroll
        for (int kk = 0; kk < 2; kk++) {
          int row = wm * 64 + (q * 2 + mi2) * 16 + (lane & 15);
          int c = ((kk << 2) + (lane >> 4)) ^ (row & 7);
          af[mi2][kk] = *(const bf16x8*)&lds[buf][row * 64 + c * 8];
        }
#pragma unroll
      for (int ni = 0; ni < 4; ni++)
#pragma unroll
        for (int kk = 0; kk < 2; kk++) {
          int row = wn * 64 + ni * 16 + (lane & 15);
          int c = ((kk << 2) + (lane >> 4)) ^ (row & 7);
          bfr[ni][kk] = *(const bf16x8*)&lds[buf][(256 + row) * 64 + c * 8];
        }
      // stage 3 loads of tile t+2
      if (st) STG(sbuf, (t + 2) << 6, q * 3, q * 3 + 2);
      if (q == 1) {
        if (st) asm volatile("s_waitcnt vmcnt(6)" ::: "memory");
        else    asm volatile("s_waitcnt vmcnt(0)" ::: "memory");
      }
      __builtin_amdgcn_s_barrier();
      __builtin_amdgcn_s_setprio(1);
#pragma unroll
      for (int mi2 = 0; mi2 < 2; mi2++)
#pragma unroll
        for (int ni = 0; ni < 4; ni++)
#pragma unroll
          for (int kk = 0; kk < 2; kk++)
            acc[q * 2 + mi2][ni] = __builtin_amdgcn_mfma_f32_16x16x32_bf16(
                af[mi2][kk], bfr[ni][kk], acc[q * 2 + mi2][ni], 0, 0, 0);
      __builtin_amdgcn_s_setprio(0);
      __builtin_amdgcn_s_barrier();
    }
    buf = (buf == 2) ? 0 : buf + 1;
    sbuf = (sbuf == 2) ? 0 : sbuf + 1;
  }

#pragma unroll
  for (int mi = 0; mi < 4; mi++)
#pragma unroll
    for (int ni = 0; ni < 4; ni++)
#pragma unroll
      for (int r = 0; r < 4; r++) {
        int row = m0 + wm * 64 + mi * 16 + (lane >> 4) * 4 + r;
        int col = n0 + wn * 64 + ni * 16 + (lane & 15);
        C[(long)row * Nn + col] = acc[mi][ni][r];
      }
}

// ---------------- RMSNorm + RoPE (+SCALE for q), fp32 -> bf16, head-major out ----------------
__global__ void __launch_bounds__(256) k_norm_rope(
    const float* __restrict__ qkv, const float* __restrict__ qns, const float* __restrict__ kns,
    unsigned short* __restrict__ qb, unsigned short* __restrict__ kb) {
  int wid = threadIdx.x >> 6, lane = threadIdx.x & 63;
  long r = (long)blockIdx.x * 4 + wid;
  int b = (int)(r / (TT * 24));
  int rem = (int)(r % (TT * 24));
  int t = rem / 24, hd = rem % 24;
  const float* row = qkv + (long)(b * TT + t) * JC + (hd < 16 ? hd * HD : 2048 + (hd - 16) * HD);
  float f0 = row[lane], f1 = row[lane + 64];
  float ss = f0 * f0 + f1 * f1;
#pragma unroll
  for (int m = 1; m < 64; m <<= 1) ss += __shfl_xor(ss, m, 64);
  float rinv = rsqrtf(ss * (1.0f / 128.0f) + 1e-6f);
  const float* sc = (hd < 16) ? qns : kns;
  float y0 = f0 * rinv * (1.0f + sc[lane]);
  float y1 = f1 * rinv * (1.0f + sc[lane + 64]);
  float ts = exp2f((float)lane * (13.287712379549449f / 64.0f));
  float ang = (float)t / ts;
  float s, c;
  sincosf(ang, &s, &c);
  float o0 = y0 * c - y1 * s;
  float o1 = y1 * c + y0 * s;
  unsigned short* dst;
  if (hd < 16) {
    o0 *= SCALE_Q; o1 *= SCALE_Q;
    dst = qb + ((long)(b * NHD + hd) * TT + t) * HD;
  } else {
    dst = kb + ((long)(b * KVH + (hd - 16)) * TT + t) * HD;
  }
  dst[lane] = f2bf(o0);
  dst[lane + 64] = f2bf(o1);
}

// ---------------- softcap -> p = exp(50*tanh(x/50) - 50) (fixed-max softmax) ----------------
template <bool FULL>
__device__ __forceinline__ void softcap16(const f32x16& s16, float* pr, float& lsum,
                                          int s_base, int tq, int g) {
#pragma unroll
  for (int r = 0; r < 16; r++) {
    float x = s16[r];
    float e = __builtin_amdgcn_exp2f(-0.05770780163555853f * fabsf(x));
    float u = (x > 0.0f ? e : 1.0f) * __builtin_amdgcn_rcpf(1.0f + e);
    float p = __builtin_amdgcn_exp2f(-144.26950408889634f * u);
    if (!FULL) {
      int s = s_base + (r & 3) + 8 * (r >> 2) + 4 * g;
      bool valid = (s <= tq) && (s > tq - WIN);
      p = valid ? p : 0.0f;
    }
    lsum += p;
    pr[r] = p;
  }
}

// half-swap across lane-32 boundary
__device__ __forceinline__ void hswap(unsigned& a, unsigned& b, int g) {
  unsigned ax = (unsigned)__shfl_xor((int)a, 32, 64);
  unsigned bx = (unsigned)__shfl_xor((int)b, 32, 64);
  unsigned r0 = g ? bx : a;
  unsigned r1 = g ? b : ax;
  a = r0; b = r1;
}

// ---------------- flash attention: QBLK=128 (4 waves x 32 rows), KVBLK=64, 32x32 MFMA ----
__global__ void __launch_bounds__(256, 2) k_attn(
    const unsigned short* __restrict__ qb, const unsigned short* __restrict__ kb,
    const unsigned short* __restrict__ vbT, unsigned short* __restrict__ enc) {
  __shared__ short Kl[2][64][128];   // [buf][s][d], XOR-swizzled 16B chunks: c ^= (s&7)
  __shared__ short Vt[2][128][64];   // [buf][h][s], XOR-swizzled 16B chunks: c ^= (h&7)
  int tid = threadIdx.x, lane = tid & 63, w = tid >> 6;
  int g = lane >> 5, l31 = lane & 31;
  int id = blockIdx.x;
  int b = id >> 8;
  int rem = id & 255;
  int n = rem >> 4;
  int traw = rem & 15;
  int tile = b ? ((traw + 8) & 15) : traw;
  int t0 = tile * 128;
  int kh = n >> 1;
  const unsigned short* qbase = qb + ((long)(b * NHD + n) * TT + t0 + w * 32) * HD;
  const unsigned short* kbase = kb + (long)(b * KVH + kh) * TT * HD;
  const unsigned short* vbase = vbT + (long)(b * KVH + kh) * HD * TT;

  bf16x8 bq[8];
  {
    const unsigned short* qp = qbase + (long)l31 * HD + g * 8;
#pragma unroll
    for (int kb8 = 0; kb8 < 8; kb8++)
      bq[kb8] = *(const bf16x8*)(qp + kb8 * 16);
  }

  f32x16 acc[4] = {};
  float lsum = 0.0f;
  int t0w = t0 + w * 32;
  int tq = t0w + l31;
  int s_begin = (t0 >= WIN) ? t0 - WIN : 0;
  int s_end = t0 + 128;

  auto STAGE = [&](int buf, int s0) {
#pragma unroll
    for (int i = 0; i < 4; i++) {
      int row = w * 16 + i * 4 + (lane >> 4);
      int c16 = (lane & 15) ^ (row & 7);
      gload16(kbase + (long)(s0 + row) * HD + c16 * 8, &Kl[buf][w * 16 + i * 4][0]);
    }
#pragma unroll
    for (int i = 0; i < 4; i++) {
      int row = w * 32 + i * 8 + (lane >> 3);
      int c16 = (lane & 7) ^ (row & 7);
      gload16(vbase + (long)row * TT + s0 + c16 * 8, &Vt[buf][w * 32 + i * 8][0]);
    }
  };

  STAGE(0, s_begin);
  __syncthreads();
  int cur = 0;
  for (int s0 = s_begin; s0 < s_end; s0 += 64) {
    if (s0 + 64 < s_end) STAGE(cur ^ 1, s0 + 64);
    bool live = (s0 <= t0w + 31) && (s0 + 63 >= t0w - (WIN - 1));
    if (live) {
      f32x16 sc2[2] = {};
#pragma unroll
      for (int sb = 0; sb < 2; sb++) {
        int srow = sb * 32 + l31;
#pragma unroll
        for (int kb8 = 0; kb8 < 8; kb8++) {
          bf16x8 ak = *(const bf16x8*)&Kl[cur][srow][8 * ((2 * kb8 + g) ^ (srow & 7))];
          sc2[sb] = __builtin_amdgcn_mfma_f32_32x32x16_bf16(ak, bq[kb8], sc2[sb], 0, 0, 0);
        }
      }
      bool full = (s0 + 63 <= t0w) && (s0 >= t0w + 31 - (WIN - 1));
      unsigned pw[4][4];
#pragma unroll
      for (int sb = 0; sb < 2; sb++) {
        float pr[16];
        if (full) softcap16<true>(sc2[sb], pr, lsum, 0, tq, g);
        else      softcap16<false>(sc2[sb], pr, lsum, s0 + sb * 32, tq, g);
        unsigned X[4], Y[4];
#pragma unroll
        for (int m = 0; m < 4; m++) {
          asm("v_cvt_pk_bf16_f32 %0, %1, %2" : "=v"(X[m]) : "v"(pr[4 * m]), "v"(pr[4 * m + 1]));
          asm("v_cvt_pk_bf16_f32 %0, %1, %2" : "=v"(Y[m]) : "v"(pr[4 * m + 2]), "v"(pr[4 * m + 3]));
        }
#pragma unroll
        for (int kl = 0; kl < 2; kl++) {
          hswap(X[2 * kl], X[2 * kl + 1], g);
          hswap(Y[2 * kl], Y[2 * kl + 1], g);
          pw[sb * 2 + kl][0] = X[2 * kl];
          pw[sb * 2 + kl][1] = Y[2 * kl];
          pw[sb * 2 + kl][2] = X[2 * kl + 1];
          pw[sb * 2 + kl][3] = Y[2 * kl + 1];
        }
      }
#pragma unroll
      for (int ks = 0; ks < 4; ks++) {
        u32x4 t4 = {pw[ks][0], pw[ks][1], pw[ks][2], pw[ks][3]};
        bf16x8 pb = __builtin_bit_cast(bf16x8, t4);
#pragma unroll
        for (int ht = 0; ht < 4; ht++) {
          int hrow = ht * 32 + l31;
          bf16x8 av = *(const bf16x8*)&Vt[cur][hrow][8 * ((2 * ks + g) ^ (hrow & 7))];
          acc[ht] = __builtin_amdgcn_mfma_f32_32x32x16_bf16(av, pb, acc[ht], 0, 0, 0);
        }
      }
    }
    __syncthreads();
    cur ^= 1;
  }

  lsum += __shfl_xor(lsum, 32, 64);
  float inv = __builtin_amdgcn_rcpf(lsum);
  unsigned short* dst = enc + ((long)(b * TT + tq) * NHD + n) * HD;
#pragma unroll
  for (int ht = 0; ht < 4; ht++)
#pragma unroll
    for (int r4 = 0; r4 < 4; r4++) {
      us4 o;
#pragma unroll
      for (int e = 0; e < 4; e++) o[e] = f2bf(acc[ht][r4 * 4 + e] * inv);
      *(us4*)(dst + ht * 32 + 8 * r4 + 4 * g) = o;
    }
}

extern "C" void kernel_launch(void* const* d_in, const int* in_sizes, int n_in,
                              void* d_out, int out_size, void* d_ws, size_t ws_size,
                              hipStream_t stream) {
  const float* x    = (const float*)d_in[0];
  const float* q_w  = (const float*)d_in[1];
  const float* kv_w = (const float*)d_in[2];
  const float* o_w  = (const float*)d_in[3];
  const float* qns  = (const float*)d_in[4];
  const float* kns  = (const float*)d_in[5];

  if (ws_size < (104ull << 20)) return;
  char* ws = (char*)d_ws;
  float*          qkv  = (float*)(ws + 0);                      // 64 MB (dead after norm/vT)
  unsigned short* enc  = (unsigned short*)(ws + 0);             // alias over dead qkv
  unsigned short* x_bf = (unsigned short*)(ws + (64ll << 20));  // 16 MB (dead after gemm1)
  unsigned short* qb   = (unsigned short*)(ws + (64ll << 20));  // alias over dead x_bf
  unsigned short* Wt   = (unsigned short*)(ws + (80ll << 20));  // 16 MB (dead after gemm1)
  unsigned short* kb   = (unsigned short*)(ws + (80ll << 20));  // alias over dead Wt
  unsigned short* vbT  = (unsigned short*)(ws + (88ll << 20));  // alias over dead Wt
  unsigned short* Wt_o = (unsigned short*)(ws + (96ll << 20));  // 8 MB, persists

  dim3 tb(32, 8, 1);
  k_cvt<<<8192, 256, 0, stream>>>((const float4*)x, (us4*)x_bf, 2097152);
  k_transpose_cvt<<<dim3(4, 64, 16), tb, 0, stream>>>(q_w, Wt, 2048, 128, 128,
                                                      0, 16, (long)2048 * 128, (long)128 * 2048);
  k_transpose_cvt<<<dim3(4, 64, 8), tb, 0, stream>>>(kv_w, Wt + (long)2048 * 2048, 2048, 128, 128,
                                                     0, 8, (long)2048 * 128, (long)128 * 2048);
  k_transpose_cvt<<<dim3(4, 64, 8), tb, 0, stream>>>(kv_w + (long)8 * 2048 * 128, Wt + (long)3072 * 2048,
                                                     2048, 128, 128, 0, 8, (long)2048 * 128, (long)128 * 2048);
  k_transpose_cvt<<<dim3(64, 64, 1), tb, 0, stream>>>(o_w, Wt_o, 2048, 2048, 2048, 0, 1, 0, 0);
  // qkv = x @ W : M=4096, N=4096, K=2048 -> grid 16 x 32 = 512
  k_gemm8<<<512, 512, 0, stream>>>(x_bf, Wt, qkv, 4096, 4096, 2048, 32);
  k_transpose_cvt<<<dim3(4, 64, 16), tb, 0, stream>>>(qkv + 3072, vbT, 2048, 128, 4096,
                                                      (long)2048 * 4096, 8, 128, (long)128 * 2048);
  k_norm_rope<<<24576, 256, 0, stream>>>(qkv, qns, kns, qb, kb);
  k_attn<<<512, 256, 0, stream>>>(qb, kb, vbT, enc);
  // out = enc @ o_w : M=4096, N=2048, K=2048 -> grid 16 x 16 = 256
  k_gemm8<<<256, 512, 0, stream>>>(enc, Wt_o, (float*)d_out, 4096, 2048, 2048, 16);
}

// Round 4
// 232.102 us; speedup vs baseline: 1.3474x; 1.0331x over previous
//
#include <hip/hip_runtime.h>
#include <stdint.h>

#define BB 2
#define TT 2048
#define DD 2048
#define NHD 16
#define KVH 8
#define HD 128
#define JC 4096          // qkv gemm output cols: q 2048 | k 1024 | v 1024
#define WIN 1024
#define SCALE_Q 0.08838834764831845f  // 1/sqrt(128)

typedef __attribute__((ext_vector_type(8))) short bf16x8;
typedef __attribute__((ext_vector_type(8))) unsigned short us8;
typedef __attribute__((ext_vector_type(4))) unsigned short us4;
typedef __attribute__((ext_vector_type(4))) float f32x4;
typedef __attribute__((ext_vector_type(16))) float f32x16;
typedef __attribute__((ext_vector_type(4))) unsigned int u32x4;

#define GAS __attribute__((address_space(1)))
#define LAS __attribute__((address_space(3)))

__device__ __forceinline__ unsigned short f2bf(float f) {
  unsigned u = __float_as_uint(f);
  u += 0x7FFFu + ((u >> 16) & 1u);   // RNE
  return (unsigned short)(u >> 16);
}

__device__ __forceinline__ void gload16(const void* g, void* l) {
  __builtin_amdgcn_global_load_lds((const GAS unsigned int*)g, (LAS unsigned int*)l, 16, 0, 0);
}

// ---------------- elementwise fp32 -> bf16 ----------------
__global__ void __launch_bounds__(256) k_cvt(const float4* __restrict__ in,
                                             us4* __restrict__ out, int n4) {
  int i = blockIdx.x * 256 + threadIdx.x;
  if (i >= n4) return;
  float4 v = in[i];
  us4 o;
  o[0] = f2bf(v.x); o[1] = f2bf(v.y); o[2] = f2bf(v.z); o[3] = f2bf(v.w);
  out[i] = o;
}

// ---------------- batched transpose + convert ----------------
__global__ void __launch_bounds__(256) k_transpose_cvt(
    const float* __restrict__ in, unsigned short* __restrict__ out,
    int R, int C, int ldin, long b0s, int nbi, long b1s, long obs) {
  __shared__ float tile[32][33];
  int z = blockIdx.z;
  const float* ib = in + (long)(z / nbi) * b0s + (long)(z % nbi) * b1s;
  unsigned short* ob = out + (long)z * obs;
  int c0 = blockIdx.x * 32, r0 = blockIdx.y * 32;
  int tx = threadIdx.x, ty = threadIdx.y;
#pragma unroll
  for (int i = 0; i < 4; i++)
    tile[ty + i * 8][tx] = ib[(long)(r0 + ty + i * 8) * ldin + c0 + tx];
  __syncthreads();
#pragma unroll
  for (int i = 0; i < 4; i++)
    ob[(long)(c0 + ty + i * 8) * R + r0 + tx] = f2bf(tile[tx][ty + i * 8]);
}

// ---------------- bf16 GEMM v3: m201-geometry 8-phase, counted vmcnt, 4-buf ----------------
// C[M,N] = A[M,K]*Bt[N,K]^T. BK=32, K=2048 (64 K-tiles). 512 thr = 8 waves (2M x 4N),
// per-wave BM/2 x 64. 4 single-K-tile LDS bufs; stage tile t+3 into buf (t+3)&3 while
// computing t (that buf's readers all completed at their lgkmcnt(0) two barriers ago ->
// provably race-free). vmcnt(2*IPT) once per K-tile: tiles t+2,t+3 stay in flight,
// t+1 guaranteed landed. Per phase: {ds_read frags || 2 gload_lds -> barrier ->
// lgkm(0)+schedbar -> setprio1 -> 16 MFMA -> setprio0 -> barrier}. B-frags read once
// per K-tile, held in registers across both M-half phases.
// LDS rows of 64B, 16B chunks XOR-swizzled: phys = c ^ (row&3) (<=2-way = free),
// staged via inverse-swizzled global source (both-sides involution).
template <int BM, int BN>
__global__ void __launch_bounds__(512, 2) k_gemm9(
    const unsigned short* __restrict__ A, const unsigned short* __restrict__ Bt,
    float* __restrict__ C, int M, int Nn, int nby) {
  constexpr int KD = 2048;
  constexpr int NT = KD / 32;
  constexpr int ROWS = BM + BN;
  constexpr int IA = BM / 128;         // A gload issues per K-tile
  constexpr int IPT = IA + BN / 128;   // total issues per K-tile
  constexpr int MT = BM / 32;          // per-wave M tiles
  constexpr int MT2 = MT / 2;          // per phase
  __shared__ short lds[4][ROWS * 32];

  int tid = threadIdx.x, lane = tid & 63, w = tid >> 6;
  int wm = w >> 2, wn = w & 3;
  int id = blockIdx.x;
  int cpx = gridDim.x >> 3;
  id = (id & 7) * cpx + (id >> 3);     // XCD swizzle (grid % 8 == 0)
  int m0 = (id / nby) * BM, n0 = (id % nby) * BN;

  // staging coords: thread tid covers row tid>>2 (of a 128-row region), 16B chunk tid&3
  int srow = tid >> 2;
  int scol = ((tid & 3) ^ (srow & 3)) * 8;   // inverse-swizzled source col (bf16)
  const unsigned short* gA = A + (long)(m0 + srow) * KD + scol;
  const unsigned short* gB = Bt + (long)(n0 + srow) * KD + scol;

  auto STG = [&](int p, int ko, int j) {
    if (j < IA)
      gload16(gA + (long)j * 128 * KD + ko, &lds[p][(j * 128 + w * 16) * 32]);
    else
      gload16(gB + (long)(j - IA) * 128 * KD + ko, &lds[p][(BM + (j - IA) * 128 + w * 16) * 32]);
  };

  // frag read: row = base + ti*16 + (lane&15); phys chunk = (lane>>4) ^ (row&3), row&3 = lane&3
  int frag = (lane & 15) * 32 + (((lane >> 4) ^ (lane & 3)) * 8);
  int abase = wm * (BM / 2) * 32 + frag;
  int bbase = (BM + wn * 64) * 32 + frag;

  f32x4 acc[MT][4] = {};
  // prologue: stage tiles 0,1,2; wait tile 0 landed (tiles 1,2 = 2*IPT in flight)
#pragma unroll
  for (int tt = 0; tt < 3; ++tt)
#pragma unroll
    for (int j = 0; j < IPT; ++j) STG(tt, tt * 32, j);
  if constexpr (IPT == 4) asm volatile("s_waitcnt vmcnt(8)" ::: "memory");
  else                    asm volatile("s_waitcnt vmcnt(6)" ::: "memory");
  __builtin_amdgcn_s_barrier();

  for (int t = 0; t < NT; ++t) {
    const short* bufp = lds[t & 3];
    bool st = (t + 3) < NT;
    int ko = (t & 31) * 32 + 96;       // ((t+3)%... constant-fold safe: (t+3)*32 - t*32*0
    ko = (t + 3) * 32;
    int sp = (t + 3) & 3;
    // ---- phase A: M-half 0 ----
    bf16x8 bfr[4], af[MT2];
#pragma unroll
    for (int ni = 0; ni < 4; ++ni)
      bfr[ni] = *(const bf16x8*)&bufp[bbase + ni * 16 * 32];
#pragma unroll
    for (int mi = 0; mi < MT2; ++mi)
      af[mi] = *(const bf16x8*)&bufp[abase + mi * 16 * 32];
    if (st) { STG(sp, ko, 0); STG(sp, ko, 1); }
    __builtin_amdgcn_s_barrier();
    asm volatile("s_waitcnt lgkmcnt(0)" ::: "memory");
    __builtin_amdgcn_sched_barrier(0);
    __builtin_amdgcn_s_setprio(1);
#pragma unroll
    for (int mi = 0; mi < MT2; ++mi)
#pragma unroll
      for (int ni = 0; ni < 4; ++ni)
        acc[mi][ni] = __builtin_amdgcn_mfma_f32_16x16x32_bf16(af[mi], bfr[ni], acc[mi][ni], 0, 0, 0);
    __builtin_amdgcn_s_setprio(0);
    __builtin_amdgcn_s_barrier();
    // ---- phase B: M-half 1 (B-frags reused from registers) ----
    bf16x8 af2[MT2];
#pragma unroll
    for (int mi = 0; mi < MT2; ++mi)
      af2[mi] = *(const bf16x8*)&bufp[abase + (MT2 + mi) * 16 * 32];
    if (st) {
#pragma unroll
      for (int j = 2; j < IPT; ++j) STG(sp, ko, j);
    }
    if constexpr (IPT == 4) {
      if (t < NT - 3)       asm volatile("s_waitcnt vmcnt(8)" ::: "memory");
      else if (t == NT - 3) asm volatile("s_waitcnt vmcnt(4)" ::: "memory");
      else if (t < NT - 1)  asm volatile("s_waitcnt vmcnt(0)" ::: "memory");
    } else {
      if (t < NT - 3)       asm volatile("s_waitcnt vmcnt(6)" ::: "memory");
      else if (t == NT - 3) asm volatile("s_waitcnt vmcnt(3)" ::: "memory");
      else if (t < NT - 1)  asm volatile("s_waitcnt vmcnt(0)" ::: "memory");
    }
    __builtin_amdgcn_s_barrier();
    asm volatile("s_waitcnt lgkmcnt(0)" ::: "memory");
    __builtin_amdgcn_sched_barrier(0);
    __builtin_amdgcn_s_setprio(1);
#pragma unroll
    for (int mi = 0; mi < MT2; ++mi)
#pragma unroll
      for (int ni = 0; ni < 4; ++ni)
        acc[MT2 + mi][ni] = __builtin_amdgcn_mfma_f32_16x16x32_bf16(af2[mi], bfr[ni], acc[MT2 + mi][ni], 0, 0, 0);
    __builtin_amdgcn_s_setprio(0);
    __builtin_amdgcn_s_barrier();
  }

#pragma unroll
  for (int mi = 0; mi < MT; mi++)
#pragma unroll
    for (int ni = 0; ni < 4; ni++)
#pragma unroll
      for (int r = 0; r < 4; r++) {
        int row = m0 + wm * (BM / 2) + mi * 16 + (lane >> 4) * 4 + r;
        int col = n0 + wn * 64 + ni * 16 + (lane & 15);
        C[(long)row * Nn + col] = acc[mi][ni][r];
      }
}

// ---------------- RMSNorm + RoPE (+SCALE for q), fp32 -> bf16, head-major out ----------------
__global__ void __launch_bounds__(256) k_norm_rope(
    const float* __restrict__ qkv, const float* __restrict__ qns, const float* __restrict__ kns,
    unsigned short* __restrict__ qb, unsigned short* __restrict__ kb) {
  int wid = threadIdx.x >> 6, lane = threadIdx.x & 63;
  long r = (long)blockIdx.x * 4 + wid;
  int b = (int)(r / (TT * 24));
  int rem = (int)(r % (TT * 24));
  int t = rem / 24, hd = rem % 24;
  const float* row = qkv + (long)(b * TT + t) * JC + (hd < 16 ? hd * HD : 2048 + (hd - 16) * HD);
  float f0 = row[lane], f1 = row[lane + 64];
  float ss = f0 * f0 + f1 * f1;
#pragma unroll
  for (int m = 1; m < 64; m <<= 1) ss += __shfl_xor(ss, m, 64);
  float rinv = rsqrtf(ss * (1.0f / 128.0f) + 1e-6f);
  const float* sc = (hd < 16) ? qns : kns;
  float y0 = f0 * rinv * (1.0f + sc[lane]);
  float y1 = f1 * rinv * (1.0f + sc[lane + 64]);
  float ts = exp2f((float)lane * (13.287712379549449f / 64.0f));
  float ang = (float)t / ts;
  float s, c;
  sincosf(ang, &s, &c);
  float o0 = y0 * c - y1 * s;
  float o1 = y1 * c + y0 * s;
  unsigned short* dst;
  if (hd < 16) {
    o0 *= SCALE_Q; o1 *= SCALE_Q;
    dst = qb + ((long)(b * NHD + hd) * TT + t) * HD;
  } else {
    dst = kb + ((long)(b * KVH + (hd - 16)) * TT + t) * HD;
  }
  dst[lane] = f2bf(o0);
  dst[lane + 64] = f2bf(o1);
}

// ---------------- softcap -> p = exp(50*tanh(x/50) - 50) (fixed-max softmax) ----------------
template <bool FULL>
__device__ __forceinline__ void softcap16(const f32x16& s16, float* pr, float& lsum,
                                          int s_base, int tq, int g) {
#pragma unroll
  for (int r = 0; r < 16; r++) {
    float x = s16[r];
    float e = __builtin_amdgcn_exp2f(-0.05770780163555853f * fabsf(x));
    float u = (x > 0.0f ? e : 1.0f) * __builtin_amdgcn_rcpf(1.0f + e);
    float p = __builtin_amdgcn_exp2f(-144.26950408889634f * u);
    if (!FULL) {
      int s = s_base + (r & 3) + 8 * (r >> 2) + 4 * g;
      bool valid = (s <= tq) && (s > tq - WIN);
      p = valid ? p : 0.0f;
    }
    lsum += p;
    pr[r] = p;
  }
}

// half-swap across lane-32 boundary
__device__ __forceinline__ void hswap(unsigned& a, unsigned& b, int g) {
  unsigned ax = (unsigned)__shfl_xor((int)a, 32, 64);
  unsigned bx = (unsigned)__shfl_xor((int)b, 32, 64);
  unsigned r0 = g ? bx : a;
  unsigned r1 = g ? b : ax;
  a = r0; b = r1;
}

// ---------------- flash attention: QBLK=128 (4 waves x 32 rows), KVBLK=64, 32x32 MFMA ----
__global__ void __launch_bounds__(256, 2) k_attn(
    const unsigned short* __restrict__ qb, const unsigned short* __restrict__ kb,
    const unsigned short* __restrict__ vbT, unsigned short* __restrict__ enc) {
  __shared__ short Kl[2][64][128];   // [buf][s][d], XOR-swizzled 16B chunks: c ^= (s&7)
  __shared__ short Vt[2][128][64];   // [buf][h][s], XOR-swizzled 16B chunks: c ^= (h&7)
  int tid = threadIdx.x, lane = tid & 63, w = tid >> 6;
  int g = lane >> 5, l31 = lane & 31;
  int id = blockIdx.x;
  int b = id >> 8;
  int rem = id & 255;
  int n = rem >> 4;
  int traw = rem & 15;
  int tile = b ? ((traw + 8) & 15) : traw;
  int t0 = tile * 128;
  int kh = n >> 1;
  const unsigned short* qbase = qb + ((long)(b * NHD + n) * TT + t0 + w * 32) * HD;
  const unsigned short* kbase = kb + (long)(b * KVH + kh) * TT * HD;
  const unsigned short* vbase = vbT + (long)(b * KVH + kh) * HD * TT;

  bf16x8 bq[8];
  {
    const unsigned short* qp = qbase + (long)l31 * HD + g * 8;
#pragma unroll
    for (int kb8 = 0; kb8 < 8; kb8++)
      bq[kb8] = *(const bf16x8*)(qp + kb8 * 16);
  }

  f32x16 acc[4] = {};
  float lsum = 0.0f;
  int t0w = t0 + w * 32;
  int tq = t0w + l31;
  int s_begin = (t0 >= WIN) ? t0 - WIN : 0;
  int s_end = t0 + 128;

  auto STAGE = [&](int buf, int s0) {
#pragma unroll
    for (int i = 0; i < 4; i++) {
      int row = w * 16 + i * 4 + (lane >> 4);
      int c16 = (lane & 15) ^ (row & 7);
      gload16(kbase + (long)(s0 + row) * HD + c16 * 8, &Kl[buf][w * 16 + i * 4][0]);
    }
#pragma unroll
    for (int i = 0; i < 4; i++) {
      int row = w * 32 + i * 8 + (lane >> 3);
      int c16 = (lane & 7) ^ (row & 7);
      gload16(vbase + (long)row * TT + s0 + c16 * 8, &Vt[buf][w * 32 + i * 8][0]);
    }
  };

  STAGE(0, s_begin);
  __syncthreads();
  int cur = 0;
  for (int s0 = s_begin; s0 < s_end; s0 += 64) {
    if (s0 + 64 < s_end) STAGE(cur ^ 1, s0 + 64);
    bool live = (s0 <= t0w + 31) && (s0 + 63 >= t0w - (WIN - 1));
    if (live) {
      f32x16 sc2[2] = {};
#pragma unroll
      for (int sb = 0; sb < 2; sb++) {
        int srow = sb * 32 + l31;
#pragma unroll
        for (int kb8 = 0; kb8 < 8; kb8++) {
          bf16x8 ak = *(const bf16x8*)&Kl[cur][srow][8 * ((2 * kb8 + g) ^ (srow & 7))];
          sc2[sb] = __builtin_amdgcn_mfma_f32_32x32x16_bf16(ak, bq[kb8], sc2[sb], 0, 0, 0);
        }
      }
      bool full = (s0 + 63 <= t0w) && (s0 >= t0w + 31 - (WIN - 1));
      unsigned pw[4][4];
#pragma unroll
      for (int sb = 0; sb < 2; sb++) {
        float pr[16];
        if (full) softcap16<true>(sc2[sb], pr, lsum, 0, tq, g);
        else      softcap16<false>(sc2[sb], pr, lsum, s0 + sb * 32, tq, g);
        unsigned X[4], Y[4];
#pragma unroll
        for (int m = 0; m < 4; m++) {
          asm("v_cvt_pk_bf16_f32 %0, %1, %2" : "=v"(X[m]) : "v"(pr[4 * m]), "v"(pr[4 * m + 1]));
          asm("v_cvt_pk_bf16_f32 %0, %1, %2" : "=v"(Y[m]) : "v"(pr[4 * m + 2]), "v"(pr[4 * m + 3]));
        }
#pragma unroll
        for (int kl = 0; kl < 2; kl++) {
          hswap(X[2 * kl], X[2 * kl + 1], g);
          hswap(Y[2 * kl], Y[2 * kl + 1], g);
          pw[sb * 2 + kl][0] = X[2 * kl];
          pw[sb * 2 + kl][1] = Y[2 * kl];
          pw[sb * 2 + kl][2] = X[2 * kl + 1];
          pw[sb * 2 + kl][3] = Y[2 * kl + 1];
        }
      }
#pragma unroll
      for (int ks = 0; ks < 4; ks++) {
        u32x4 t4 = {pw[ks][0], pw[ks][1], pw[ks][2], pw[ks][3]};
        bf16x8 pb = __builtin_bit_cast(bf16x8, t4);
#pragma unroll
        for (int ht = 0; ht < 4; ht++) {
          int hrow = ht * 32 + l31;
          bf16x8 av = *(const bf16x8*)&Vt[cur][hrow][8 * ((2 * ks + g) ^ (hrow & 7))];
          acc[ht] = __builtin_amdgcn_mfma_f32_32x32x16_bf16(av, pb, acc[ht], 0, 0, 0);
        }
      }
    }
    __syncthreads();
    cur ^= 1;
  }

  lsum += __shfl_xor(lsum, 32, 64);
  float inv = __builtin_amdgcn_rcpf(lsum);
  unsigned short* dst = enc + ((long)(b * TT + tq) * NHD + n) * HD;
#pragma unroll
  for (int ht = 0; ht < 4; ht++)
#pragma unroll
    for (int r4 = 0; r4 < 4; r4++) {
      us4 o;
#pragma unroll
      for (int e = 0; e < 4; e++) o[e] = f2bf(acc[ht][r4 * 4 + e] * inv);
      *(us4*)(dst + ht * 32 + 8 * r4 + 4 * g) = o;
    }
}

extern "C" void kernel_launch(void* const* d_in, const int* in_sizes, int n_in,
                              void* d_out, int out_size, void* d_ws, size_t ws_size,
                              hipStream_t stream) {
  const float* x    = (const float*)d_in[0];
  const float* q_w  = (const float*)d_in[1];
  const float* kv_w = (const float*)d_in[2];
  const float* o_w  = (const float*)d_in[3];
  const float* qns  = (const float*)d_in[4];
  const float* kns  = (const float*)d_in[5];

  if (ws_size < (104ull << 20)) return;
  char* ws = (char*)d_ws;
  float*          qkv  = (float*)(ws + 0);                      // 64 MB (dead after norm/vT)
  unsigned short* enc  = (unsigned short*)(ws + 0);             // alias over dead qkv
  unsigned short* x_bf = (unsigned short*)(ws + (64ll << 20));  // 16 MB (dead after gemm1)
  unsigned short* qb   = (unsigned short*)(ws + (64ll << 20));  // alias over dead x_bf
  unsigned short* Wt   = (unsigned short*)(ws + (80ll << 20));  // 16 MB (dead after gemm1)
  unsigned short* kb   = (unsigned short*)(ws + (80ll << 20));  // alias over dead Wt
  unsigned short* vbT  = (unsigned short*)(ws + (88ll << 20));  // alias over dead Wt
  unsigned short* Wt_o = (unsigned short*)(ws + (96ll << 20));  // 8 MB, persists

  dim3 tb(32, 8, 1);
  k_cvt<<<8192, 256, 0, stream>>>((const float4*)x, (us4*)x_bf, 2097152);
  k_transpose_cvt<<<dim3(4, 64, 16), tb, 0, stream>>>(q_w, Wt, 2048, 128, 128,
                                                      0, 16, (long)2048 * 128, (long)128 * 2048);
  k_transpose_cvt<<<dim3(4, 64, 8), tb, 0, stream>>>(kv_w, Wt + (long)2048 * 2048, 2048, 128, 128,
                                                     0, 8, (long)2048 * 128, (long)128 * 2048);
  k_transpose_cvt<<<dim3(4, 64, 8), tb, 0, stream>>>(kv_w + (long)8 * 2048 * 128, Wt + (long)3072 * 2048,
                                                     2048, 128, 128, 0, 8, (long)2048 * 128, (long)128 * 2048);
  k_transpose_cvt<<<dim3(64, 64, 1), tb, 0, stream>>>(o_w, Wt_o, 2048, 2048, 2048, 0, 1, 0, 0);
  // qkv = x @ W : 4096x4096, grid 16*16 = 256 blocks (1/CU)
  k_gemm9<256, 256><<<256, 512, 0, stream>>>(x_bf, Wt, qkv, 4096, 4096, 16);
  k_transpose_cvt<<<dim3(4, 64, 16), tb, 0, stream>>>(qkv + 3072, vbT, 2048, 128, 4096,
                                                      (long)2048 * 4096, 8, 128, (long)128 * 2048);
  k_norm_rope<<<24576, 256, 0, stream>>>(qkv, qns, kns, qb, kb);
  k_attn<<<512, 256, 0, stream>>>(qb, kb, vbT, enc);
  // out = enc @ o_w : 4096x2048, grid 32*8 = 256 blocks
  k_gemm9<128, 256><<<256, 512, 0, stream>>>(enc, Wt_o, (float*)d_out, 4096, 2048, 8);
}

// Round 5
// 226.819 us; speedup vs baseline: 1.3788x; 1.0233x over previous
//
#include <hip/hip_runtime.h>
#include <stdint.h>

#define BB 2
#define TT 2048
#define DD 2048
#define NHD 16
#define KVH 8
#define HD 128
#define JC 4096          // qkv gemm output cols: q 2048 | k 1024 | v 1024
#define WIN 1024
#define SCALE_Q 0.08838834764831845f  // 1/sqrt(128)

typedef __attribute__((ext_vector_type(8))) short bf16x8;
typedef __attribute__((ext_vector_type(8))) unsigned short us8;
typedef __attribute__((ext_vector_type(4))) unsigned short us4;
typedef __attribute__((ext_vector_type(4))) float f32x4;
typedef __attribute__((ext_vector_type(16))) float f32x16;
typedef __attribute__((ext_vector_type(4))) unsigned int u32x4;

#define GAS __attribute__((address_space(1)))
#define LAS __attribute__((address_space(3)))

__device__ __forceinline__ unsigned short f2bf(float f) {
  unsigned u = __float_as_uint(f);
  u += 0x7FFFu + ((u >> 16) & 1u);   // RNE
  return (unsigned short)(u >> 16);
}

__device__ __forceinline__ void gload16(const void* g, void* l) {
  __builtin_amdgcn_global_load_lds((const GAS unsigned int*)g, (LAS unsigned int*)l, 16, 0, 0);
}

// ---------------- elementwise fp32 -> bf16 ----------------
__global__ void __launch_bounds__(256) k_cvt(const float4* __restrict__ in,
                                             us4* __restrict__ out, int n4) {
  int i = blockIdx.x * 256 + threadIdx.x;
  if (i >= n4) return;
  float4 v = in[i];
  us4 o;
  o[0] = f2bf(v.x); o[1] = f2bf(v.y); o[2] = f2bf(v.z); o[3] = f2bf(v.w);
  out[i] = o;
}

// ---------------- batched transpose + convert ----------------
__global__ void __launch_bounds__(256) k_transpose_cvt(
    const float* __restrict__ in, unsigned short* __restrict__ out,
    int R, int C, int ldin, long b0s, int nbi, long b1s, long obs) {
  __shared__ float tile[32][33];
  int z = blockIdx.z;
  const float* ib = in + (long)(z / nbi) * b0s + (long)(z % nbi) * b1s;
  unsigned short* ob = out + (long)z * obs;
  int c0 = blockIdx.x * 32, r0 = blockIdx.y * 32;
  int tx = threadIdx.x, ty = threadIdx.y;
#pragma unroll
  for (int i = 0; i < 4; i++)
    tile[ty + i * 8][tx] = ib[(long)(r0 + ty + i * 8) * ldin + c0 + tx];
  __syncthreads();
#pragma unroll
  for (int i = 0; i < 4; i++)
    ob[(long)(c0 + ty + i * 8) * R + r0 + tx] = f2bf(tile[tx][ty + i * 8]);
}

// ---------------- bf16 GEMM v4: m201-geometry 8-phase, counted vmcnt, 4-buf ----------------
// Identical to R4's k_gemm9 except the LDS swizzle: phys_chunk = chunk ^ ((row>>1)&3)
// (was chunk ^ (row&3)). Bank math: 64B rows = 16 banks; a frag-read's 16-lane group
// (rows 0..15, fixed logical chunk g) now lands on 8 distinct (chunk, row-parity) bank
// positions for rows 0..7 (rows 8..15 alias 2-way = free). Old swizzle collided at
// row 4 -> 4-way conflict -> 6.3e6 conflict cycles -> LDS-pipe-bound at 34% MfmaUtil.
template <int BM, int BN>
__global__ void __launch_bounds__(512, 2) k_gemm9(
    const unsigned short* __restrict__ A, const unsigned short* __restrict__ Bt,
    float* __restrict__ C, int M, int Nn, int nby) {
  constexpr int KD = 2048;
  constexpr int NT = KD / 32;
  constexpr int ROWS = BM + BN;
  constexpr int IA = BM / 128;         // A gload issues per K-tile
  constexpr int IPT = IA + BN / 128;   // total issues per K-tile
  constexpr int MT = BM / 32;          // per-wave M tiles
  constexpr int MT2 = MT / 2;          // per phase
  __shared__ short lds[4][ROWS * 32];

  int tid = threadIdx.x, lane = tid & 63, w = tid >> 6;
  int wm = w >> 2, wn = w & 3;
  int id = blockIdx.x;
  int cpx = gridDim.x >> 3;
  id = (id & 7) * cpx + (id >> 3);     // XCD swizzle (grid % 8 == 0)
  int m0 = (id / nby) * BM, n0 = (id % nby) * BN;

  // staging: thread tid covers row tid>>2 (of a 128-row region), phys 16B chunk tid&3.
  // source logical chunk = (tid&3) ^ ((row>>1)&3) = (tid&3) ^ ((tid>>3)&3)
  int srow = tid >> 2;
  int scol = ((tid & 3) ^ ((tid >> 3) & 3)) * 8;
  const unsigned short* gA = A + (long)(m0 + srow) * KD + scol;
  const unsigned short* gB = Bt + (long)(n0 + srow) * KD + scol;

  auto STG = [&](int p, int ko, int j) {
    if (j < IA)
      gload16(gA + (long)j * 128 * KD + ko, &lds[p][(j * 128 + w * 16) * 32]);
    else
      gload16(gB + (long)(j - IA) * 128 * KD + ko, &lds[p][(BM + (j - IA) * 128 + w * 16) * 32]);
  };

  // frag read: row = base + ti*16 + (lane&15); all bases are multiples of 64 rows ->
  // (row>>1)&3 = (lane>>1)&3; phys chunk = (lane>>4) ^ ((lane>>1)&3)
  int frag = (lane & 15) * 32 + (((lane >> 4) ^ ((lane >> 1) & 3)) * 8);
  int abase = wm * (BM / 2) * 32 + frag;
  int bbase = (BM + wn * 64) * 32 + frag;

  f32x4 acc[MT][4] = {};
  // prologue: stage tiles 0,1,2; wait tile 0 landed (tiles 1,2 = 2*IPT in flight)
#pragma unroll
  for (int tt = 0; tt < 3; ++tt)
#pragma unroll
    for (int j = 0; j < IPT; ++j) STG(tt, tt * 32, j);
  if constexpr (IPT == 4) asm volatile("s_waitcnt vmcnt(8)" ::: "memory");
  else                    asm volatile("s_waitcnt vmcnt(6)" ::: "memory");
  __builtin_amdgcn_s_barrier();

  for (int t = 0; t < NT; ++t) {
    const short* bufp = lds[t & 3];
    bool st = (t + 3) < NT;
    int ko = (t + 3) * 32;
    int sp = (t + 3) & 3;
    // ---- phase A: M-half 0 ----
    bf16x8 bfr[4], af[MT2];
#pragma unroll
    for (int ni = 0; ni < 4; ++ni)
      bfr[ni] = *(const bf16x8*)&bufp[bbase + ni * 16 * 32];
#pragma unroll
    for (int mi = 0; mi < MT2; ++mi)
      af[mi] = *(const bf16x8*)&bufp[abase + mi * 16 * 32];
    if (st) { STG(sp, ko, 0); STG(sp, ko, 1); }
    __builtin_amdgcn_s_barrier();
    asm volatile("s_waitcnt lgkmcnt(0)" ::: "memory");
    __builtin_amdgcn_sched_barrier(0);
    __builtin_amdgcn_s_setprio(1);
#pragma unroll
    for (int mi = 0; mi < MT2; ++mi)
#pragma unroll
      for (int ni = 0; ni < 4; ++ni)
        acc[mi][ni] = __builtin_amdgcn_mfma_f32_16x16x32_bf16(af[mi], bfr[ni], acc[mi][ni], 0, 0, 0);
    __builtin_amdgcn_s_setprio(0);
    __builtin_amdgcn_s_barrier();
    // ---- phase B: M-half 1 (B-frags reused from registers) ----
    bf16x8 af2[MT2];
#pragma unroll
    for (int mi = 0; mi < MT2; ++mi)
      af2[mi] = *(const bf16x8*)&bufp[abase + (MT2 + mi) * 16 * 32];
    if (st) {
#pragma unroll
      for (int j = 2; j < IPT; ++j) STG(sp, ko, j);
    }
    if constexpr (IPT == 4) {
      if (t < NT - 3)       asm volatile("s_waitcnt vmcnt(8)" ::: "memory");
      else if (t == NT - 3) asm volatile("s_waitcnt vmcnt(4)" ::: "memory");
      else if (t < NT - 1)  asm volatile("s_waitcnt vmcnt(0)" ::: "memory");
    } else {
      if (t < NT - 3)       asm volatile("s_waitcnt vmcnt(6)" ::: "memory");
      else if (t == NT - 3) asm volatile("s_waitcnt vmcnt(3)" ::: "memory");
      else if (t < NT - 1)  asm volatile("s_waitcnt vmcnt(0)" ::: "memory");
    }
    __builtin_amdgcn_s_barrier();
    asm volatile("s_waitcnt lgkmcnt(0)" ::: "memory");
    __builtin_amdgcn_sched_barrier(0);
    __builtin_amdgcn_s_setprio(1);
#pragma unroll
    for (int mi = 0; mi < MT2; ++mi)
#pragma unroll
      for (int ni = 0; ni < 4; ++ni)
        acc[MT2 + mi][ni] = __builtin_amdgcn_mfma_f32_16x16x32_bf16(af2[mi], bfr[ni], acc[MT2 + mi][ni], 0, 0, 0);
    __builtin_amdgcn_s_setprio(0);
    __builtin_amdgcn_s_barrier();
  }

#pragma unroll
  for (int mi = 0; mi < MT; mi++)
#pragma unroll
    for (int ni = 0; ni < 4; ni++)
#pragma unroll
      for (int r = 0; r < 4; r++) {
        int row = m0 + wm * (BM / 2) + mi * 16 + (lane >> 4) * 4 + r;
        int col = n0 + wn * 64 + ni * 16 + (lane & 15);
        C[(long)row * Nn + col] = acc[mi][ni][r];
      }
}

// ---------------- RMSNorm + RoPE (+SCALE for q), fp32 -> bf16, head-major out ----------------
__global__ void __launch_bounds__(256) k_norm_rope(
    const float* __restrict__ qkv, const float* __restrict__ qns, const float* __restrict__ kns,
    unsigned short* __restrict__ qb, unsigned short* __restrict__ kb) {
  int wid = threadIdx.x >> 6, lane = threadIdx.x & 63;
  long r = (long)blockIdx.x * 4 + wid;
  int b = (int)(r / (TT * 24));
  int rem = (int)(r % (TT * 24));
  int t = rem / 24, hd = rem % 24;
  const float* row = qkv + (long)(b * TT + t) * JC + (hd < 16 ? hd * HD : 2048 + (hd - 16) * HD);
  float f0 = row[lane], f1 = row[lane + 64];
  float ss = f0 * f0 + f1 * f1;
#pragma unroll
  for (int m = 1; m < 64; m <<= 1) ss += __shfl_xor(ss, m, 64);
  float rinv = rsqrtf(ss * (1.0f / 128.0f) + 1e-6f);
  const float* sc = (hd < 16) ? qns : kns;
  float y0 = f0 * rinv * (1.0f + sc[lane]);
  float y1 = f1 * rinv * (1.0f + sc[lane + 64]);
  float ts = exp2f((float)lane * (13.287712379549449f / 64.0f));
  float ang = (float)t / ts;
  float s, c;
  sincosf(ang, &s, &c);
  float o0 = y0 * c - y1 * s;
  float o1 = y1 * c + y0 * s;
  unsigned short* dst;
  if (hd < 16) {
    o0 *= SCALE_Q; o1 *= SCALE_Q;
    dst = qb + ((long)(b * NHD + hd) * TT + t) * HD;
  } else {
    dst = kb + ((long)(b * KVH + (hd - 16)) * TT + t) * HD;
  }
  dst[lane] = f2bf(o0);
  dst[lane + 64] = f2bf(o1);
}

// ---------------- softcap -> p = exp(50*tanh(x/50) - 50) (fixed-max softmax) ----------------
template <bool FULL>
__device__ __forceinline__ void softcap16(const f32x16& s16, float* pr, float& lsum,
                                          int s_base, int tq, int g) {
#pragma unroll
  for (int r = 0; r < 16; r++) {
    float x = s16[r];
    float e = __builtin_amdgcn_exp2f(-0.05770780163555853f * fabsf(x));
    float u = (x > 0.0f ? e : 1.0f) * __builtin_amdgcn_rcpf(1.0f + e);
    float p = __builtin_amdgcn_exp2f(-144.26950408889634f * u);
    if (!FULL) {
      int s = s_base + (r & 3) + 8 * (r >> 2) + 4 * g;
      bool valid = (s <= tq) && (s > tq - WIN);
      p = valid ? p : 0.0f;
    }
    lsum += p;
    pr[r] = p;
  }
}

// half-swap across lane-32 boundary
__device__ __forceinline__ void hswap(unsigned& a, unsigned& b, int g) {
  unsigned ax = (unsigned)__shfl_xor((int)a, 32, 64);
  unsigned bx = (unsigned)__shfl_xor((int)b, 32, 64);
  unsigned r0 = g ? bx : a;
  unsigned r1 = g ? b : ax;
  a = r0; b = r1;
}

// ---------------- flash attention: QBLK=128 (4 waves x 32 rows), KVBLK=64, 32x32 MFMA ----
__global__ void __launch_bounds__(256, 2) k_attn(
    const unsigned short* __restrict__ qb, const unsigned short* __restrict__ kb,
    const unsigned short* __restrict__ vbT, unsigned short* __restrict__ enc) {
  __shared__ short Kl[2][64][128];   // [buf][s][d], XOR-swizzled 16B chunks: c ^= (s&7)
  __shared__ short Vt[2][128][64];   // [buf][h][s], XOR-swizzled 16B chunks: c ^= (h&7)
  int tid = threadIdx.x, lane = tid & 63, w = tid >> 6;
  int g = lane >> 5, l31 = lane & 31;
  int id = blockIdx.x;
  int b = id >> 8;
  int rem = id & 255;
  int n = rem >> 4;
  int traw = rem & 15;
  int tile = b ? ((traw + 8) & 15) : traw;
  int t0 = tile * 128;
  int kh = n >> 1;
  const unsigned short* qbase = qb + ((long)(b * NHD + n) * TT + t0 + w * 32) * HD;
  const unsigned short* kbase = kb + (long)(b * KVH + kh) * TT * HD;
  const unsigned short* vbase = vbT + (long)(b * KVH + kh) * HD * TT;

  bf16x8 bq[8];
  {
    const unsigned short* qp = qbase + (long)l31 * HD + g * 8;
#pragma unroll
    for (int kb8 = 0; kb8 < 8; kb8++)
      bq[kb8] = *(const bf16x8*)(qp + kb8 * 16);
  }

  f32x16 acc[4] = {};
  float lsum = 0.0f;
  int t0w = t0 + w * 32;
  int tq = t0w + l31;
  int s_begin = (t0 >= WIN) ? t0 - WIN : 0;
  int s_end = t0 + 128;

  auto STAGE = [&](int buf, int s0) {
#pragma unroll
    for (int i = 0; i < 4; i++) {
      int row = w * 16 + i * 4 + (lane >> 4);
      int c16 = (lane & 15) ^ (row & 7);
      gload16(kbase + (long)(s0 + row) * HD + c16 * 8, &Kl[buf][w * 16 + i * 4][0]);
    }
#pragma unroll
    for (int i = 0; i < 4; i++) {
      int row = w * 32 + i * 8 + (lane >> 3);
      int c16 = (lane & 7) ^ (row & 7);
      gload16(vbase + (long)row * TT + s0 + c16 * 8, &Vt[buf][w * 32 + i * 8][0]);
    }
  };

  STAGE(0, s_begin);
  __syncthreads();
  int cur = 0;
  for (int s0 = s_begin; s0 < s_end; s0 += 64) {
    if (s0 + 64 < s_end) STAGE(cur ^ 1, s0 + 64);
    bool live = (s0 <= t0w + 31) && (s0 + 63 >= t0w - (WIN - 1));
    if (live) {
      f32x16 sc2[2] = {};
#pragma unroll
      for (int sb = 0; sb < 2; sb++) {
        int srow = sb * 32 + l31;
#pragma unroll
        for (int kb8 = 0; kb8 < 8; kb8++) {
          bf16x8 ak = *(const bf16x8*)&Kl[cur][srow][8 * ((2 * kb8 + g) ^ (srow & 7))];
          sc2[sb] = __builtin_amdgcn_mfma_f32_32x32x16_bf16(ak, bq[kb8], sc2[sb], 0, 0, 0);
        }
      }
      bool full = (s0 + 63 <= t0w) && (s0 >= t0w + 31 - (WIN - 1));
      unsigned pw[4][4];
#pragma unroll
      for (int sb = 0; sb < 2; sb++) {
        float pr[16];
        if (full) softcap16<true>(sc2[sb], pr, lsum, 0, tq, g);
        else      softcap16<false>(sc2[sb], pr, lsum, s0 + sb * 32, tq, g);
        unsigned X[4], Y[4];
#pragma unroll
        for (int m = 0; m < 4; m++) {
          asm("v_cvt_pk_bf16_f32 %0, %1, %2" : "=v"(X[m]) : "v"(pr[4 * m]), "v"(pr[4 * m + 1]));
          asm("v_cvt_pk_bf16_f32 %0, %1, %2" : "=v"(Y[m]) : "v"(pr[4 * m + 2]), "v"(pr[4 * m + 3]));
        }
#pragma unroll
        for (int kl = 0; kl < 2; kl++) {
          hswap(X[2 * kl], X[2 * kl + 1], g);
          hswap(Y[2 * kl], Y[2 * kl + 1], g);
          pw[sb * 2 + kl][0] = X[2 * kl];
          pw[sb * 2 + kl][1] = Y[2 * kl];
          pw[sb * 2 + kl][2] = X[2 * kl + 1];
          pw[sb * 2 + kl][3] = Y[2 * kl + 1];
        }
      }
#pragma unroll
      for (int ks = 0; ks < 4; ks++) {
        u32x4 t4 = {pw[ks][0], pw[ks][1], pw[ks][2], pw[ks][3]};
        bf16x8 pb = __builtin_bit_cast(bf16x8, t4);
#pragma unroll
        for (int ht = 0; ht < 4; ht++) {
          int hrow = ht * 32 + l31;
          bf16x8 av = *(const bf16x8*)&Vt[cur][hrow][8 * ((2 * ks + g) ^ (hrow & 7))];
          acc[ht] = __builtin_amdgcn_mfma_f32_32x32x16_bf16(av, pb, acc[ht], 0, 0, 0);
        }
      }
    }
    __syncthreads();
    cur ^= 1;
  }

  lsum += __shfl_xor(lsum, 32, 64);
  float inv = __builtin_amdgcn_rcpf(lsum);
  unsigned short* dst = enc + ((long)(b * TT + tq) * NHD + n) * HD;
#pragma unroll
  for (int ht = 0; ht < 4; ht++)
#pragma unroll
    for (int r4 = 0; r4 < 4; r4++) {
      us4 o;
#pragma unroll
      for (int e = 0; e < 4; e++) o[e] = f2bf(acc[ht][r4 * 4 + e] * inv);
      *(us4*)(dst + ht * 32 + 8 * r4 + 4 * g) = o;
    }
}

extern "C" void kernel_launch(void* const* d_in, const int* in_sizes, int n_in,
                              void* d_out, int out_size, void* d_ws, size_t ws_size,
                              hipStream_t stream) {
  const float* x    = (const float*)d_in[0];
  const float* q_w  = (const float*)d_in[1];
  const float* kv_w = (const float*)d_in[2];
  const float* o_w  = (const float*)d_in[3];
  const float* qns  = (const float*)d_in[4];
  const float* kns  = (const float*)d_in[5];

  if (ws_size < (104ull << 20)) return;
  char* ws = (char*)d_ws;
  float*          qkv  = (float*)(ws + 0);                      // 64 MB (dead after norm/vT)
  unsigned short* enc  = (unsigned short*)(ws + 0);             // alias over dead qkv
  unsigned short* x_bf = (unsigned short*)(ws + (64ll << 20));  // 16 MB (dead after gemm1)
  unsigned short* qb   = (unsigned short*)(ws + (64ll << 20));  // alias over dead x_bf
  unsigned short* Wt   = (unsigned short*)(ws + (80ll << 20));  // 16 MB (dead after gemm1)
  unsigned short* kb   = (unsigned short*)(ws + (80ll << 20));  // alias over dead Wt
  unsigned short* vbT  = (unsigned short*)(ws + (88ll << 20));  // alias over dead Wt
  unsigned short* Wt_o = (unsigned short*)(ws + (96ll << 20));  // 8 MB, persists

  dim3 tb(32, 8, 1);
  k_cvt<<<8192, 256, 0, stream>>>((const float4*)x, (us4*)x_bf, 2097152);
  k_transpose_cvt<<<dim3(4, 64, 16), tb, 0, stream>>>(q_w, Wt, 2048, 128, 128,
                                                      0, 16, (long)2048 * 128, (long)128 * 2048);
  k_transpose_cvt<<<dim3(4, 64, 8), tb, 0, stream>>>(kv_w, Wt + (long)2048 * 2048, 2048, 128, 128,
                                                     0, 8, (long)2048 * 128, (long)128 * 2048);
  k_transpose_cvt<<<dim3(4, 64, 8), tb, 0, stream>>>(kv_w + (long)8 * 2048 * 128, Wt + (long)3072 * 2048,
                                                     2048, 128, 128, 0, 8, (long)2048 * 128, (long)128 * 2048);
  k_transpose_cvt<<<dim3(64, 64, 1), tb, 0, stream>>>(o_w, Wt_o, 2048, 2048, 2048, 0, 1, 0, 0);
  // qkv = x @ W : 4096x4096, grid 16*16 = 256 blocks (1/CU)
  k_gemm9<256, 256><<<256, 512, 0, stream>>>(x_bf, Wt, qkv, 4096, 4096, 16);
  k_transpose_cvt<<<dim3(4, 64, 16), tb, 0, stream>>>(qkv + 3072, vbT, 2048, 128, 4096,
                                                      (long)2048 * 4096, 8, 128, (long)128 * 2048);
  k_norm_rope<<<24576, 256, 0, stream>>>(qkv, qns, kns, qb, kb);
  k_attn<<<512, 256, 0, stream>>>(qb, kb, vbT, enc);
  // out = enc @ o_w : 4096x2048, grid 32*8 = 256 blocks
  k_gemm9<128, 256><<<256, 512, 0, stream>>>(enc, Wt_o, (float*)d_out, 4096, 2048, 8);
}